// Round 9
// baseline (305.126 us; speedup 1.0000x reference)
//
#include <hip/hip_runtime.h>
#include <math.h>

// PartitionedTransformerEncoderLayer on MI355X — round 9.
// vs round 8: k_qkv_g and k_ffn1 move to gemm_core2 — 256x128 block, 4 waves,
// wave-tile 128x64 (acc[8][4]). LDS-reads per FLOP drop 1.33x (16 reads/0.52MF
// -> 24 reads/1.05MF); 64 MFMA amortize each barrier pair. oproj/ffn2 keep the
// 128x128 core (N too thin for 256 tiles). attn/prep/LN untouched.

namespace {

typedef unsigned short u16;
typedef __attribute__((ext_vector_type(8))) short s16x8;
typedef __attribute__((ext_vector_type(4))) float f32x4;

__device__ inline u16 f2bf(float f) {
  union { float f; unsigned u; } c; c.f = f;
  unsigned u = c.u;
  return (u16)((u + 0x7fffu + ((u >> 16) & 1u)) >> 16);
}

__device__ inline float bf2f(u16 v) {
  union { unsigned u; float f; } c; c.u = ((unsigned)v) << 16; return c.f;
}

__device__ inline void gl16(const void* g, void* l) {
  __builtin_amdgcn_global_load_lds(
      (const __attribute__((address_space(1))) unsigned int*)g,
      (__attribute__((address_space(3))) unsigned int*)l, 16, 0, 0);
}

__device__ inline s16x8 ldf(const void* p) { return *(const s16x8*)p; }

__device__ inline f32x4 mfma16(s16x8 a, s16x8 b, f32x4 c) {
  return __builtin_amdgcn_mfma_f32_16x16x32_bf16(a, b, c, 0, 0, 0);
}

#define WAITVM8() asm volatile("s_waitcnt vmcnt(8)" ::: "memory")
#define WAITVM0() asm volatile("s_waitcnt vmcnt(0)" ::: "memory")

// ---------------- GEMM core 1: 128x128, 4 waves, wave-tile 64x64 ----------------
__device__ inline void gemm_core(const char* gA, long stepA, long rs32A,
                                 const char* gB, long stepB, long rs32B,
                                 int ksteps, char* AsB, char* BsB, int t,
                                 f32x4 acc[4][4])
{
  const int l = t & 63;
  const int w = t >> 6;
  const int wr = w >> 1, wc = w & 1;
  const int lswz = (l & 7) << 4;
  const int wofs = w * 1024;
  int aoff[4][2], boff[4][2];
#pragma unroll
  for (int mi = 0; mi < 4; ++mi)
#pragma unroll
    for (int c = 0; c < 2; ++c) {
      aoff[mi][c] = (wr*64 + mi*16 + (l & 15))*128 + ((c*64 + ((l >> 4)*16)) ^ lswz);
      boff[mi][c] = (wc*64 + mi*16 + (l & 15))*128 + ((c*64 + ((l >> 4)*16)) ^ lswz);
    }
  for (int ks = 0; ks < ksteps; ++ks) {
#pragma unroll
    for (int is = 0; is < 4; ++is) {
      gl16(gA + is*rs32A, AsB + is*4096 + wofs);
      gl16(gB + is*rs32B, BsB + is*4096 + wofs);
    }
    gA += stepA; gB += stepB;
    __syncthreads();
    s16x8 af[4][2], bf[4][2];
#pragma unroll
    for (int mi = 0; mi < 4; ++mi)
#pragma unroll
      for (int c = 0; c < 2; ++c) {
        af[mi][c] = ldf(AsB + aoff[mi][c]);
        bf[mi][c] = ldf(BsB + boff[mi][c]);
      }
#pragma unroll
    for (int mi = 0; mi < 4; ++mi)
#pragma unroll
      for (int nj = 0; nj < 4; ++nj)
#pragma unroll
        for (int c = 0; c < 2; ++c)
          acc[mi][nj] = mfma16(af[mi][c], bf[nj][c], acc[mi][nj]);
    __syncthreads();
  }
}

// ---------------- GEMM core 2: 256x128, 4 waves, wave-tile 128x64 ----------------
// As 32KB (8 stage-issues), Bs 16KB (4 issues). acc[8][4] = 128 VGPR.
__device__ inline void gemm_core2(const char* gA, long stepA, long rs32A,
                                  const char* gB, long stepB, long rs32B,
                                  int ksteps, char* AsB, char* BsB, int t,
                                  f32x4 acc[8][4])
{
  const int l = t & 63;
  const int w = t >> 6;
  const int wr = w >> 1, wc = w & 1;
  const int lswz = (l & 7) << 4;
  const int g = l >> 4;
  const int wofs = w * 1024;
  int aoff[8][2], boff[4][2];
#pragma unroll
  for (int mi = 0; mi < 8; ++mi)
#pragma unroll
    for (int c = 0; c < 2; ++c)
      aoff[mi][c] = (wr*128 + mi*16 + (l & 15))*128 + ((c*64 + g*16) ^ lswz);
#pragma unroll
  for (int nj = 0; nj < 4; ++nj)
#pragma unroll
    for (int c = 0; c < 2; ++c)
      boff[nj][c] = (wc*64 + nj*16 + (l & 15))*128 + ((c*64 + g*16) ^ lswz);
  for (int ks = 0; ks < ksteps; ++ks) {
#pragma unroll
    for (int is = 0; is < 8; ++is)
      gl16(gA + is*rs32A, AsB + is*4096 + wofs);
#pragma unroll
    for (int is = 0; is < 4; ++is)
      gl16(gB + is*rs32B, BsB + is*4096 + wofs);
    gA += stepA; gB += stepB;
    __syncthreads();
#pragma unroll
    for (int c = 0; c < 2; ++c) {
      s16x8 bf[4];
#pragma unroll
      for (int nj = 0; nj < 4; ++nj) bf[nj] = ldf(BsB + boff[nj][c]);
#pragma unroll
      for (int mi = 0; mi < 8; ++mi) {
        s16x8 af = ldf(AsB + aoff[mi][c]);
#pragma unroll
        for (int nj = 0; nj < 4; ++nj)
          acc[mi][nj] = mfma16(af, bf[nj], acc[mi][nj]);
      }
    }
    __syncthreads();
  }
}

// ---------------- merged prep: cast x, cast FFN weights, transpose wo, wqkv ---------
__global__ __launch_bounds__(256) void k_prep(
    const float* __restrict__ x,
    const float* __restrict__ w1c, const float* __restrict__ w1p,
    const float* __restrict__ w2c, const float* __restrict__ w2p,
    const float* __restrict__ woc, const float* __restrict__ wop,
    const float* __restrict__ wqc, const float* __restrict__ wqp,
    u16* __restrict__ xb, u16* __restrict__ w1b, u16* __restrict__ w2b,
    u16* __restrict__ wot, u16* __restrict__ Bqt)
{
  __shared__ float tile[32][33];
  const int bid = blockIdx.x;
  const int t = threadIdx.x;
  if (bid < 4096) {
    const int i = bid*256 + t;
    float4 v = reinterpret_cast<const float4*>(x)[i];
    uint2 pk;
    pk.x = (unsigned)f2bf(v.x) | ((unsigned)f2bf(v.y) << 16);
    pk.y = (unsigned)f2bf(v.z) | ((unsigned)f2bf(v.w) << 16);
    reinterpret_cast<uint2*>(xb)[i] = pk;
  } else if (bid < 8192) {
    const int j = bid - 4096;
    const float* src; u16* dst;
    switch (j >> 10) {
      case 0:  src = w1c; dst = w1b;            break;
      case 1:  src = w1p; dst = w1b + 1048576;  break;
      case 2:  src = w2c; dst = w2b;            break;
      default: src = w2p; dst = w2b + 1048576;  break;
    }
    const int i = (j & 1023)*256 + t;
    float4 v = reinterpret_cast<const float4*>(src)[i];
    uint2 pk;
    pk.x = (unsigned)f2bf(v.x) | ((unsigned)f2bf(v.y) << 16);
    pk.y = (unsigned)f2bf(v.z) | ((unsigned)f2bf(v.w) << 16);
    reinterpret_cast<uint2*>(dst)[i] = pk;
  } else if (bid < 8704) {
    const int j = bid - 8192;
    const int half = j >> 8, rem = j & 255;
    const int r0 = (rem >> 4) * 32, c0 = (rem & 15) * 32;
    const float* in = half ? wop : woc;
    u16* o = wot + (size_t)half * 512 * 512;
    const int tx = t & 31, ty = t >> 5;
#pragma unroll
    for (int jj = 0; jj < 4; ++jj)
      tile[ty + 8*jj][tx] = in[(size_t)(r0 + ty + 8*jj)*512 + c0 + tx];
    __syncthreads();
#pragma unroll
    for (int jj = 0; jj < 4; ++jj)
      o[(size_t)(c0 + ty + 8*jj)*512 + r0 + tx] = f2bf(tile[tx][ty + 8*jj]);
  } else {
    const int j = bid - 8704;
    const int z = j / 96, rem = j - z*96;
    const int by = rem / 6, bx = rem - by*6;
    const int half = z >> 3, h = z & 7;
    const float* in = (half ? wqp : wqc) + (size_t)h * 98304;   // [f=512][ca=192]
    u16* o = Bqt + (size_t)half * 786432 + (size_t)h * 98304;   // [ca=192][f=512]
    const int r0 = by * 32, c0 = bx * 32;
    const int tx = t & 31, ty = t >> 5;
#pragma unroll
    for (int jj = 0; jj < 4; ++jj)
      tile[ty + 8*jj][tx] = in[(size_t)(r0 + ty + 8*jj)*192 + c0 + tx];
    __syncthreads();
#pragma unroll
    for (int jj = 0; jj < 4; ++jj)
      o[(size_t)(c0 + ty + 8*jj)*512 + r0 + tx] = f2bf(tile[tx][ty + 8*jj]);
  }
}

// ---------------- QKV projection GEMM (core2: 256x128) ----------------
// grid (16, 12, 2). M=4096, N=1536, K=512 per half.
__global__ __launch_bounds__(256) void k_qkv_g(
    const u16* __restrict__ xb, const u16* __restrict__ Bqt,
    u16* __restrict__ Qb, u16* __restrict__ Kb, u16* __restrict__ Vtb)
{
  __shared__ char As[32768], Bs[16384];
  const int t = threadIdx.x;
  const int mt = blockIdx.x, nt = blockIdx.y, half = blockIdx.z;
  const int rowA = t >> 3;
  const int insw = (((t & 7) ^ (rowA & 7)) << 4);
  const char* gA = (const char*)xb + half*1024 + (size_t)(mt*256 + rowA)*2048 + insw;
  const char* gB = (const char*)(Bqt + (size_t)half*786432) + (size_t)(nt*128 + rowA)*1024 + insw;
  f32x4 acc[8][4] = {};
  gemm_core2(gA, 128, 32L*2048, gB, 128, 32L*1024, 8, As, Bs, t, acc);
  const int l = t & 63, w = t >> 6, wr = w >> 1, wc = w & 1, g = l >> 4;
#pragma unroll
  for (int nj = 0; nj < 4; ++nj) {
    const int gc = nt*128 + wc*64 + nj*16 + (l & 15);
    const int h = gc / 192, rem = gc - h*192;
    const int cc = rem >> 6, a = rem & 63;
#pragma unroll
    for (int mi = 0; mi < 8; ++mi) {
#pragma unroll
      for (int r = 0; r < 4; ++r) {
        const int gr = mt*256 + wr*128 + mi*16 + g*4 + r;
        const int b = gr >> 10, tok = gr & 1023;
        const float v = acc[mi][nj][r];
        if (cc == 0)
          Qb[((size_t)((b*8 + h)*1024 + tok))*128 + half*64 + a] =
              f2bf(v * 0.08838834764831843f);
        else if (cc == 1)
          Kb[((size_t)((b*8 + h)*1024 + tok))*128 + half*64 + a] = f2bf(v);
        else
          Vtb[((size_t)((b*8 + h)*128 + half*64 + a))*1024 + tok] = f2bf(v);
      }
    }
  }
}

// ---------------- MFMA flash attention (swapped QK^T, in-lane softmax) ----------------
__global__ __launch_bounds__(256) void k_attn(
    const u16* __restrict__ Qb, const u16* __restrict__ Kb,
    const u16* __restrict__ Vtb, u16* __restrict__ Ob)
{
  __shared__ char Ks[2 * 16384];   // K tiles [64 tok][128B d] swizzled, dbuf
  __shared__ char Vs[2 * 16384];   // Vt tiles [128 d][128B tok] swizzled, dbuf
  __shared__ u16 Pl[4 * 16 * 64];  // per-wave P [16 q][64 k] u16, XOR-swizzled
  const int t = threadIdx.x;
  const int l = t & 63, w = t >> 6;
  const int g = l >> 4;            // 16-lane group 0..3
  const int qt = blockIdx.x, bh = blockIdx.y;
  const size_t cb = (size_t)bh * 1024 * 128;
  const int q0 = qt*64 + w*16;
  const int lswz = (l & 7) << 4;

  s16x8 qf[4];   // B-frag of Q^T: col q = l&15
#pragma unroll
  for (int dc = 0; dc < 4; ++dc)
    qf[dc] = ldf((const char*)(Qb + cb) + (size_t)(q0 + (l & 15))*256 + dc*64 + (g*16));

  f32x4 o[8];
#pragma unroll
  for (int dc = 0; dc < 8; ++dc) o[dc] = (f32x4){0.f, 0.f, 0.f, 0.f};
  float mrun = -INFINITY, lrun = 0.f;   // per-lane: q = l&15

  const int krow = t >> 4;
  const int kins = (((t & 15) ^ (krow & 7)) << 4);
  const char* gK0 = (const char*)(Kb + cb) + (size_t)krow*256 + kins;
  const int vrow = t >> 3;
  const int vins = (((t & 7) ^ (vrow & 7)) << 4);
  const char* gV0 = (const char*)(Vtb + cb) + (size_t)vrow*2048 + vins;

  auto stage = [&](int kt, int buf) {
    char* kd = Ks + buf*16384 + w*1024;
    char* vd = Vs + buf*16384 + w*1024;
#pragma unroll
    for (int is = 0; is < 4; ++is) {
      gl16(gK0 + (size_t)kt*16384 + (size_t)is*16*256, kd + is*4096);
      gl16(gV0 + (size_t)kt*128 + (size_t)is*32*2048, vd + is*4096);
    }
  };

  char* pwB = (char*)(Pl + w*1024);           // 2KB per wave, row stride 128B
  const int prow = (l & 15);
  const int pkey = (prow & 7) << 4;
  const int pread0 = prow*128 + ((0*64 + g*16) ^ pkey);
  const int pread1 = prow*128 + ((1*64 + g*16) ^ pkey);
  const int srcbase = l & 48;                  // for alpha/lrun cross-layout shfl

  auto qkstep = [&](int kt, int cur) {
    if (kt < 15) { stage(kt + 1, cur ^ 1); WAITVM8(); }
    else         { WAITVM0(); }
    __builtin_amdgcn_sched_barrier(0);
    __builtin_amdgcn_s_barrier();
    const char* Kc = Ks + cur*16384;
    const char* Vc = Vs + cur*16384;
    // QK^T swapped: s[kf] = K_frag * Q^T_frag -> C[k][q], q = l&15 lane-local
    f32x4 s[4];
#pragma unroll
    for (int kf = 0; kf < 4; ++kf) s[kf] = (f32x4){0.f, 0.f, 0.f, 0.f};
    __builtin_amdgcn_s_setprio(1);
#pragma unroll
    for (int dc = 0; dc < 4; ++dc) {
#pragma unroll
      for (int kf = 0; kf < 4; ++kf) {
        s16x8 kfr = ldf(Kc + (kf*16 + (l & 15))*256 + ((dc*64 + g*16) ^ lswz));
        s[kf] = mfma16(kfr, qf[dc], s[kf]);
      }
    }
    __builtin_amdgcn_s_setprio(0);
    // in-lane softmax over 16 regs, then 2 shuffles
    float m01, m23, pmax;
    m01 = fmaxf(fmaxf(s[0][0], s[0][1]), fmaxf(s[0][2], s[0][3]));
    m23 = fmaxf(fmaxf(s[1][0], s[1][1]), fmaxf(s[1][2], s[1][3]));
    pmax = fmaxf(m01, m23);
    m01 = fmaxf(fmaxf(s[2][0], s[2][1]), fmaxf(s[2][2], s[2][3]));
    m23 = fmaxf(fmaxf(s[3][0], s[3][1]), fmaxf(s[3][2], s[3][3]));
    pmax = fmaxf(pmax, fmaxf(m01, m23));
    pmax = fmaxf(pmax, __shfl_xor(pmax, 16));
    pmax = fmaxf(pmax, __shfl_xor(pmax, 32));
    const bool skip = __all(pmax <= mrun + 8.0f);   // defer-max THR=8
    float mnew, alpha;
    if (skip) { mnew = mrun; alpha = 1.0f; }
    else      { mnew = fmaxf(mrun, pmax); alpha = __expf(mrun - mnew); }
    float psum = 0.f;
#pragma unroll
    for (int kf = 0; kf < 4; ++kf) {
#pragma unroll
      for (int r = 0; r < 4; ++r) {
        const float p = __expf(s[kf][r] - mnew);
        s[kf][r] = p;
        psum += p;
      }
    }
    psum += __shfl_xor(psum, 16);
    psum += __shfl_xor(psum, 32);
    lrun = lrun * alpha + psum;
    mrun = mnew;
    if (!skip) {
      float a4[4];
#pragma unroll
      for (int r = 0; r < 4; ++r) a4[r] = __shfl(alpha, srcbase | (g*4 + r));
#pragma unroll
      for (int dc = 0; dc < 8; ++dc)
#pragma unroll
        for (int r = 0; r < 4; ++r) o[dc][r] *= a4[r];
    }
    // P -> per-wave LDS: row q = l&15, 4 x 8B packed
#pragma unroll
    for (int kf = 0; kf < 4; ++kf) {
      uint2 pk;
      pk.x = (unsigned)f2bf(s[kf][0]) | ((unsigned)f2bf(s[kf][1]) << 16);
      pk.y = (unsigned)f2bf(s[kf][2]) | ((unsigned)f2bf(s[kf][3]) << 16);
      *(uint2*)(pwB + prow*128 + ((kf*32 + g*8) ^ pkey)) = pk;
    }
    s16x8 pa[2];
    pa[0] = ldf(pwB + pread0);
    pa[1] = ldf(pwB + pread1);
    // PV
    __builtin_amdgcn_s_setprio(1);
#pragma unroll
    for (int dc = 0; dc < 8; ++dc) {
#pragma unroll
      for (int c = 0; c < 2; ++c) {
        s16x8 vf = ldf(Vc + (dc*16 + (l & 15))*128 + ((c*64 + g*16) ^ lswz));
        o[dc] = mfma16(pa[c], vf, o[dc]);
      }
    }
    __builtin_amdgcn_s_setprio(0);
    __builtin_amdgcn_s_barrier();
  };

  stage(0, 0);
  for (int kt = 0; kt < 16; kt += 2) {
    qkstep(kt, 0);
    qkstep(kt + 1, 1);
  }

  float linv[4];
#pragma unroll
  for (int r = 0; r < 4; ++r)
    linv[r] = 1.0f / __shfl(lrun, srcbase | (g*4 + r));
#pragma unroll
  for (int r = 0; r < 4; ++r) {
    const int q = q0 + g*4 + r;
#pragma unroll
    for (int dc = 0; dc < 8; ++dc)
      Ob[cb + (size_t)q*128 + dc*16 + (l & 15)] = f2bf(o[dc][r] * linv[r]);
  }
}

// ---------------- output projection (+residual), core1 ----------------
__global__ __launch_bounds__(256) void k_oproj(
    const u16* __restrict__ Ob, const u16* __restrict__ wot,
    const float* __restrict__ x, float* __restrict__ s1)
{
  __shared__ char As[16384], Bs[16384];
  const int t = threadIdx.x;
  const int mt = blockIdx.x, nt = blockIdx.y, half = blockIdx.z;
  const int rowA = t >> 3;
  const int insw = (((t & 7) ^ (rowA & 7)) << 4);
  const int b = mt >> 3;
  const char* gA = (const char*)Ob + ((size_t)(b*8)*1024 + (mt & 7)*128 + rowA)*256
                   + half*128 + insw;
  const char* gB = (const char*)(wot + (size_t)half*262144) + (size_t)(nt*128 + rowA)*1024 + insw;
  f32x4 acc[4][4] = {};
  gemm_core(gA, 262144, 32L*256, gB, 128, 32L*1024, 8, As, Bs, t, acc);
  const int l = t & 63, w = t >> 6, wr = w >> 1, wc = w & 1;
#pragma unroll
  for (int mi = 0; mi < 4; ++mi)
#pragma unroll
    for (int r = 0; r < 4; ++r) {
      const int gr = mt*128 + wr*64 + mi*16 + ((l >> 4) << 2) + r;
#pragma unroll
      for (int nj = 0; nj < 4; ++nj) {
        const int col = half*512 + nt*128 + wc*64 + nj*16 + (l & 15);
        const size_t idx = (size_t)gr*1024 + col;
        s1[idx] = acc[mi][nj][r] + x[idx];
      }
    }
}

// ---------------- FFN1 (bias+ReLU), core2: grid (16,16,2) ----------------
__global__ __launch_bounds__(256) void k_ffn1(
    const u16* __restrict__ x1b, const u16* __restrict__ w1b,
    const float* __restrict__ b1c, const float* __restrict__ b1p,
    u16* __restrict__ hb)
{
  __shared__ char As[32768], Bs[16384];
  const int t = threadIdx.x;
  const int mt = blockIdx.x, nt = blockIdx.y, half = blockIdx.z;
  const int rowA = t >> 3;
  const int insw = (((t & 7) ^ (rowA & 7)) << 4);
  const char* gA = (const char*)x1b + half*1024 + (size_t)(mt*256 + rowA)*2048 + insw;
  const char* gB = (const char*)w1b + (size_t)half*2097152 + (size_t)(nt*128 + rowA)*1024 + insw;
  const float* bb = half ? b1p : b1c;
  f32x4 acc[8][4] = {};
  gemm_core2(gA, 128, 32L*2048, gB, 128, 32L*1024, 8, As, Bs, t, acc);
  const int l = t & 63, w = t >> 6, wr = w >> 1, wc = w & 1, g = l >> 4;
#pragma unroll
  for (int nj = 0; nj < 4; ++nj) {
    const int n = nt*128 + wc*64 + nj*16 + (l & 15);
    const float bias = bb[n];
#pragma unroll
    for (int mi = 0; mi < 8; ++mi) {
#pragma unroll
      for (int r = 0; r < 4; ++r) {
        const int gr = mt*256 + wr*128 + mi*16 + g*4 + r;
        hb[(size_t)gr*4096 + half*2048 + n] = f2bf(fmaxf(acc[mi][nj][r] + bias, 0.f));
      }
    }
  }
}

// ---------------- FFN2 (bias + bf16 residual), core1: grid (32,4,2) ---------
__global__ __launch_bounds__(256) void k_ffn2(
    const u16* __restrict__ hb, const u16* __restrict__ w2b,
    const float* __restrict__ b2c, const float* __restrict__ b2p,
    const u16* __restrict__ x1b, float* __restrict__ s2)
{
  __shared__ char As[16384], Bs[16384];
  const int t = threadIdx.x;
  const int mt = blockIdx.x, nt = blockIdx.y, half = blockIdx.z;
  const int rowA = t >> 3;
  const int insw = (((t & 7) ^ (rowA & 7)) << 4);
  const char* gA = (const char*)hb + (size_t)(mt*128 + rowA)*8192 + half*4096 + insw;
  const char* gB = (const char*)w2b + (size_t)half*2097152 + (size_t)(nt*128 + rowA)*4096 + insw;
  const float* bb = half ? b2p : b2c;
  f32x4 acc[4][4] = {};
  gemm_core(gA, 128, 32L*8192, gB, 128, 32L*4096, 32, As, Bs, t, acc);
  const int l = t & 63, w = t >> 6, wr = w >> 1, wc = w & 1;
#pragma unroll
  for (int mi = 0; mi < 4; ++mi)
#pragma unroll
    for (int r = 0; r < 4; ++r) {
      const int gr = mt*128 + wr*64 + mi*16 + ((l >> 4) << 2) + r;
#pragma unroll
      for (int nj = 0; nj < 4; ++nj) {
        const int nloc = nt*128 + wc*64 + nj*16 + (l & 15);
        const size_t idx = (size_t)gr*1024 + half*512 + nloc;
        s2[idx] = acc[mi][nj][r] + bb[nloc] + bf2f(x1b[idx]);
      }
    }
}

// ---------------- LayerNorm: wave-per-row, 4 rows/block, grid 1024 ----------------
__global__ __launch_bounds__(256) void k_ln4(
    const float* __restrict__ in, const float* __restrict__ g,
    const float* __restrict__ be, float* __restrict__ outf, u16* __restrict__ outb)
{
  const int t = threadIdx.x;
  const int l = t & 63;
  const int row = blockIdx.x*4 + (t >> 6);
  const float4* src = reinterpret_cast<const float4*>(in + (size_t)row*1024);
  float4 v[4];
  float s = 0.f, ss = 0.f;
#pragma unroll
  for (int j = 0; j < 4; ++j) {
    v[j] = src[l + 64*j];
    s  += v[j].x + v[j].y + v[j].z + v[j].w;
    ss += v[j].x*v[j].x + v[j].y*v[j].y + v[j].z*v[j].z + v[j].w*v[j].w;
  }
#pragma unroll
  for (int off = 1; off < 64; off <<= 1) {
    s  += __shfl_xor(s, off);
    ss += __shfl_xor(ss, off);
  }
  const float mu = s * (1.f/1024.f);
  const float var = ss * (1.f/1024.f) - mu*mu;
  const float rs = rsqrtf(var + 1e-5f);
#pragma unroll
  for (int j = 0; j < 4; ++j) {
    const int c4 = l + 64*j;
    float4 gv = reinterpret_cast<const float4*>(g)[c4];
    float4 bv = reinterpret_cast<const float4*>(be)[c4];
    float4 ov;
    ov.x = (v[j].x - mu)*rs*gv.x + bv.x;
    ov.y = (v[j].y - mu)*rs*gv.y + bv.y;
    ov.z = (v[j].z - mu)*rs*gv.z + bv.z;
    ov.w = (v[j].w - mu)*rs*gv.w + bv.w;
    if (outf)
      reinterpret_cast<float4*>(outf + (size_t)row*1024)[c4] = ov;
    if (outb) {
      uint2 pk;
      pk.x = (unsigned)f2bf(ov.x) | ((unsigned)f2bf(ov.y) << 16);
      pk.y = (unsigned)f2bf(ov.z) | ((unsigned)f2bf(ov.w) << 16);
      reinterpret_cast<uint2*>(outb + (size_t)row*1024)[c4] = pk;
    }
  }
}

}  // namespace

extern "C" void kernel_launch(void* const* d_in, const int* in_sizes, int n_in,
                              void* d_out, int out_size, void* d_ws, size_t ws_size,
                              hipStream_t stream)
{
  (void)in_sizes; (void)n_in; (void)out_size; (void)ws_size;
  const float* x      = (const float*)d_in[0];
  const float* wqkv_c = (const float*)d_in[2];
  const float* wqkv_p = (const float*)d_in[3];
  const float* wo_c   = (const float*)d_in[4];
  const float* wo_p   = (const float*)d_in[5];
  const float* w1_c   = (const float*)d_in[6];
  const float* b1_c   = (const float*)d_in[7];
  const float* w1_p   = (const float*)d_in[8];
  const float* b1_p   = (const float*)d_in[9];
  const float* w2_c   = (const float*)d_in[10];
  const float* b2_c   = (const float*)d_in[11];
  const float* w2_p   = (const float*)d_in[12];
  const float* b2_p   = (const float*)d_in[13];
  const float* ln1_g  = (const float*)d_in[14];
  const float* ln1_b  = (const float*)d_in[15];
  const float* ln2_g  = (const float*)d_in[16];
  const float* ln2_b  = (const float*)d_in[17];

  // workspace layout (bytes)
  char* W = (char*)d_ws;
  u16*   xb  = (u16*)(W);                      // 8MB; Ob aliases after QKV
  u16*   Ob  = xb;
  u16*   Qb  = (u16*)(W + (8u  << 20));        // 8MB [b,h,tok,128]
  u16*   Kb  = (u16*)(W + (16u << 20));        // 8MB
  u16*   Vtb = (u16*)(W + (24u << 20));        // 8MB [b,h,d,tok]
  u16*   Bqt = (u16*)(W + (32u << 20));        // 3MB [2][1536][512]
  u16*   wot = (u16*)(W + (35u << 20));        // 1MB [2][512][512]
  u16*   w1b = (u16*)(W + (36u << 20));        // 4MB [2][2048][512]
  u16*   w2b = (u16*)(W + (40u << 20));        // 4MB [2][512][2048]
  float* s1  = (float*)(W + (44u << 20));      // 16MB fp32 (attn+res, then ffn+res)
  u16*   x1b = (u16*)(W + (60u << 20));        // 8MB bf16 LN1 output
  u16*   hb  = (u16*)(W + (68u << 20));        // 32MB [4096][4096] (half-interleaved)
  float* out = (float*)d_out;

  k_prep <<<10240, 256, 0, stream>>>(x, w1_c, w1_p, w2_c, w2_p,
                                     wo_c, wo_p, wqkv_c, wqkv_p,
                                     xb, w1b, w2b, wot, Bqt);
  k_qkv_g<<<dim3(16, 12, 2), 256, 0, stream>>>(xb, Bqt, Qb, Kb, Vtb);
  k_attn <<<dim3(16, 32),    256, 0, stream>>>(Qb, Kb, Vtb, Ob);
  k_oproj<<<dim3(32, 4, 2),  256, 0, stream>>>(Ob, wot, x, s1);
  k_ln4  <<<1024,            256, 0, stream>>>(s1, ln1_g, ln1_b, nullptr, x1b);
  k_ffn1 <<<dim3(16, 16, 2), 256, 0, stream>>>(x1b, w1b, b1_c, b1_p, hb);
  k_ffn2 <<<dim3(32, 4, 2),  256, 0, stream>>>(hb, w2b, b2_c, b2_p, x1b, s1);
  k_ln4  <<<1024,            256, 0, stream>>>(s1, ln2_g, ln2_b, out, nullptr);
}

// Round 10
// 266.188 us; speedup vs baseline: 1.1463x; 1.1463x over previous
//
#include <hip/hip_runtime.h>
#include <math.h>

// PartitionedTransformerEncoderLayer on MI355X — round 10.
// vs round 9 (FAILED: 256x128 tile cut grid to 1.5 blocks/CU, exposed staging
// latency, qkv 97us): revert qkv/ffn1 to round-8 core1. New: gemm_core_db for
// the 1-block/CU kernels (oproj, ffn2) — double-buffered LDS, stage-ahead with
// counted vmcnt(8) + raw barriers (same pattern proven race-free in k_attn).
// attn/prep/LN untouched.

namespace {

typedef unsigned short u16;
typedef __attribute__((ext_vector_type(8))) short s16x8;
typedef __attribute__((ext_vector_type(4))) float f32x4;

__device__ inline u16 f2bf(float f) {
  union { float f; unsigned u; } c; c.f = f;
  unsigned u = c.u;
  return (u16)((u + 0x7fffu + ((u >> 16) & 1u)) >> 16);
}

__device__ inline float bf2f(u16 v) {
  union { unsigned u; float f; } c; c.u = ((unsigned)v) << 16; return c.f;
}

__device__ inline void gl16(const void* g, void* l) {
  __builtin_amdgcn_global_load_lds(
      (const __attribute__((address_space(1))) unsigned int*)g,
      (__attribute__((address_space(3))) unsigned int*)l, 16, 0, 0);
}

__device__ inline s16x8 ldf(const void* p) { return *(const s16x8*)p; }

__device__ inline f32x4 mfma16(s16x8 a, s16x8 b, f32x4 c) {
  return __builtin_amdgcn_mfma_f32_16x16x32_bf16(a, b, c, 0, 0, 0);
}

#define WAITVM8() asm volatile("s_waitcnt vmcnt(8)" ::: "memory")
#define WAITVM0() asm volatile("s_waitcnt vmcnt(0)" ::: "memory")

// ---------------- GEMM core 1: 128x128, 4 waves, wave-tile 64x64 ----------------
// For kernels with >=2 blocks/CU (implicit wave-level overlap hides staging).
__device__ inline void gemm_core(const char* gA, long stepA, long rs32A,
                                 const char* gB, long stepB, long rs32B,
                                 int ksteps, char* AsB, char* BsB, int t,
                                 f32x4 acc[4][4])
{
  const int l = t & 63;
  const int w = t >> 6;
  const int wr = w >> 1, wc = w & 1;
  const int lswz = (l & 7) << 4;
  const int wofs = w * 1024;
  int aoff[4][2], boff[4][2];
#pragma unroll
  for (int mi = 0; mi < 4; ++mi)
#pragma unroll
    for (int c = 0; c < 2; ++c) {
      aoff[mi][c] = (wr*64 + mi*16 + (l & 15))*128 + ((c*64 + ((l >> 4)*16)) ^ lswz);
      boff[mi][c] = (wc*64 + mi*16 + (l & 15))*128 + ((c*64 + ((l >> 4)*16)) ^ lswz);
    }
  for (int ks = 0; ks < ksteps; ++ks) {
#pragma unroll
    for (int is = 0; is < 4; ++is) {
      gl16(gA + is*rs32A, AsB + is*4096 + wofs);
      gl16(gB + is*rs32B, BsB + is*4096 + wofs);
    }
    gA += stepA; gB += stepB;
    __syncthreads();
    s16x8 af[4][2], bf[4][2];
#pragma unroll
    for (int mi = 0; mi < 4; ++mi)
#pragma unroll
      for (int c = 0; c < 2; ++c) {
        af[mi][c] = ldf(AsB + aoff[mi][c]);
        bf[mi][c] = ldf(BsB + boff[mi][c]);
      }
#pragma unroll
    for (int mi = 0; mi < 4; ++mi)
#pragma unroll
      for (int nj = 0; nj < 4; ++nj)
#pragma unroll
        for (int c = 0; c < 2; ++c)
          acc[mi][nj] = mfma16(af[mi][c], bf[nj][c], acc[mi][nj]);
    __syncthreads();
  }
}

// ---------------- GEMM core DB: 128x128, double-buffered, stage-ahead ----------------
// For 1-block/CU kernels (no co-resident waves to hide latency). AsB/BsB are
// 2x16KB. Next tile's 8 gl16 issued before computing current; vmcnt(8) waits
// only for the current tile. Same sync pattern as k_attn (race-analyzed:
// buffer `cur` is re-staged two iterations later, after the trailing barrier).
__device__ inline void gemm_core_db(const char* gA, long stepA, long rs32A,
                                    const char* gB, long stepB, long rs32B,
                                    int ksteps, char* AsB, char* BsB, int t,
                                    f32x4 acc[4][4])
{
  const int l = t & 63;
  const int w = t >> 6;
  const int wr = w >> 1, wc = w & 1;
  const int lswz = (l & 7) << 4;
  const int wofs = w * 1024;
  int aoff[4][2], boff[4][2];
#pragma unroll
  for (int mi = 0; mi < 4; ++mi)
#pragma unroll
    for (int c = 0; c < 2; ++c) {
      aoff[mi][c] = (wr*64 + mi*16 + (l & 15))*128 + ((c*64 + ((l >> 4)*16)) ^ lswz);
      boff[mi][c] = (wc*64 + mi*16 + (l & 15))*128 + ((c*64 + ((l >> 4)*16)) ^ lswz);
    }
  auto stage = [&](int ks, int buf) {
    const char* A = gA + (long)ks*stepA;
    const char* B = gB + (long)ks*stepB;
    char* ad = AsB + buf*16384 + wofs;
    char* bd = BsB + buf*16384 + wofs;
#pragma unroll
    for (int is = 0; is < 4; ++is) {
      gl16(A + is*rs32A, ad + is*4096);
      gl16(B + is*rs32B, bd + is*4096);
    }
  };
  stage(0, 0);
  for (int ks = 0; ks < ksteps; ++ks) {
    const int cur = ks & 1;
    if (ks + 1 < ksteps) { stage(ks + 1, cur ^ 1); WAITVM8(); }
    else                 { WAITVM0(); }
    __builtin_amdgcn_sched_barrier(0);
    __builtin_amdgcn_s_barrier();
    const char* Ac = AsB + cur*16384;
    const char* Bc = BsB + cur*16384;
    s16x8 af[4][2], bf[4][2];
#pragma unroll
    for (int mi = 0; mi < 4; ++mi)
#pragma unroll
      for (int c = 0; c < 2; ++c) {
        af[mi][c] = ldf(Ac + aoff[mi][c]);
        bf[mi][c] = ldf(Bc + boff[mi][c]);
      }
    __builtin_amdgcn_s_setprio(1);
#pragma unroll
    for (int mi = 0; mi < 4; ++mi)
#pragma unroll
      for (int nj = 0; nj < 4; ++nj)
#pragma unroll
        for (int c = 0; c < 2; ++c)
          acc[mi][nj] = mfma16(af[mi][c], bf[nj][c], acc[mi][nj]);
    __builtin_amdgcn_s_setprio(0);
    __builtin_amdgcn_s_barrier();
  }
}

// ---------------- merged prep: cast x, cast FFN weights, transpose wo, wqkv ---------
__global__ __launch_bounds__(256) void k_prep(
    const float* __restrict__ x,
    const float* __restrict__ w1c, const float* __restrict__ w1p,
    const float* __restrict__ w2c, const float* __restrict__ w2p,
    const float* __restrict__ woc, const float* __restrict__ wop,
    const float* __restrict__ wqc, const float* __restrict__ wqp,
    u16* __restrict__ xb, u16* __restrict__ w1b, u16* __restrict__ w2b,
    u16* __restrict__ wot, u16* __restrict__ Bqt)
{
  __shared__ float tile[32][33];
  const int bid = blockIdx.x;
  const int t = threadIdx.x;
  if (bid < 4096) {
    const int i = bid*256 + t;
    float4 v = reinterpret_cast<const float4*>(x)[i];
    uint2 pk;
    pk.x = (unsigned)f2bf(v.x) | ((unsigned)f2bf(v.y) << 16);
    pk.y = (unsigned)f2bf(v.z) | ((unsigned)f2bf(v.w) << 16);
    reinterpret_cast<uint2*>(xb)[i] = pk;
  } else if (bid < 8192) {
    const int j = bid - 4096;
    const float* src; u16* dst;
    switch (j >> 10) {
      case 0:  src = w1c; dst = w1b;            break;
      case 1:  src = w1p; dst = w1b + 1048576;  break;
      case 2:  src = w2c; dst = w2b;            break;
      default: src = w2p; dst = w2b + 1048576;  break;
    }
    const int i = (j & 1023)*256 + t;
    float4 v = reinterpret_cast<const float4*>(src)[i];
    uint2 pk;
    pk.x = (unsigned)f2bf(v.x) | ((unsigned)f2bf(v.y) << 16);
    pk.y = (unsigned)f2bf(v.z) | ((unsigned)f2bf(v.w) << 16);
    reinterpret_cast<uint2*>(dst)[i] = pk;
  } else if (bid < 8704) {
    const int j = bid - 8192;
    const int half = j >> 8, rem = j & 255;
    const int r0 = (rem >> 4) * 32, c0 = (rem & 15) * 32;
    const float* in = half ? wop : woc;
    u16* o = wot + (size_t)half * 512 * 512;
    const int tx = t & 31, ty = t >> 5;
#pragma unroll
    for (int jj = 0; jj < 4; ++jj)
      tile[ty + 8*jj][tx] = in[(size_t)(r0 + ty + 8*jj)*512 + c0 + tx];
    __syncthreads();
#pragma unroll
    for (int jj = 0; jj < 4; ++jj)
      o[(size_t)(c0 + ty + 8*jj)*512 + r0 + tx] = f2bf(tile[tx][ty + 8*jj]);
  } else {
    const int j = bid - 8704;
    const int z = j / 96, rem = j - z*96;
    const int by = rem / 6, bx = rem - by*6;
    const int half = z >> 3, h = z & 7;
    const float* in = (half ? wqp : wqc) + (size_t)h * 98304;   // [f=512][ca=192]
    u16* o = Bqt + (size_t)half * 786432 + (size_t)h * 98304;   // [ca=192][f=512]
    const int r0 = by * 32, c0 = bx * 32;
    const int tx = t & 31, ty = t >> 5;
#pragma unroll
    for (int jj = 0; jj < 4; ++jj)
      tile[ty + 8*jj][tx] = in[(size_t)(r0 + ty + 8*jj)*192 + c0 + tx];
    __syncthreads();
#pragma unroll
    for (int jj = 0; jj < 4; ++jj)
      o[(size_t)(c0 + ty + 8*jj)*512 + r0 + tx] = f2bf(tile[tx][ty + 8*jj]);
  }
}

// ---------------- QKV projection GEMM (core1, round-8 config) ----------------
__global__ __launch_bounds__(256) void k_qkv_g(
    const u16* __restrict__ xb, const u16* __restrict__ Bqt,
    u16* __restrict__ Qb, u16* __restrict__ Kb, u16* __restrict__ Vtb)
{
  __shared__ char As[16384], Bs[16384];
  const int t = threadIdx.x;
  const int mt = blockIdx.x, nt = blockIdx.y, half = blockIdx.z;
  const int rowA = t >> 3;
  const int insw = (((t & 7) ^ (rowA & 7)) << 4);
  const char* gA = (const char*)xb + half*1024 + (size_t)(mt*128 + rowA)*2048 + insw;
  const char* gB = (const char*)(Bqt + (size_t)half*786432) + (size_t)(nt*128 + rowA)*1024 + insw;
  f32x4 acc[4][4] = {};
  gemm_core(gA, 128, 32L*2048, gB, 128, 32L*1024, 8, As, Bs, t, acc);
  const int l = t & 63, w = t >> 6, wr = w >> 1, wc = w & 1;
#pragma unroll
  for (int nj = 0; nj < 4; ++nj) {
    const int gc = nt*128 + wc*64 + nj*16 + (l & 15);
    const int h = gc / 192, rem = gc - h*192;
    const int cc = rem >> 6, a = rem & 63;
#pragma unroll
    for (int mi = 0; mi < 4; ++mi) {
#pragma unroll
      for (int r = 0; r < 4; ++r) {
        const int gr = mt*128 + wr*64 + mi*16 + ((l >> 4) << 2) + r;
        const int b = gr >> 10, tok = gr & 1023;
        const float v = acc[mi][nj][r];
        if (cc == 0)
          Qb[((size_t)((b*8 + h)*1024 + tok))*128 + half*64 + a] =
              f2bf(v * 0.08838834764831843f);
        else if (cc == 1)
          Kb[((size_t)((b*8 + h)*1024 + tok))*128 + half*64 + a] = f2bf(v);
        else
          Vtb[((size_t)((b*8 + h)*128 + half*64 + a))*1024 + tok] = f2bf(v);
      }
    }
  }
}

// ---------------- MFMA flash attention (swapped QK^T, in-lane softmax) ----------------
__global__ __launch_bounds__(256) void k_attn(
    const u16* __restrict__ Qb, const u16* __restrict__ Kb,
    const u16* __restrict__ Vtb, u16* __restrict__ Ob)
{
  __shared__ char Ks[2 * 16384];   // K tiles [64 tok][128B d] swizzled, dbuf
  __shared__ char Vs[2 * 16384];   // Vt tiles [128 d][128B tok] swizzled, dbuf
  __shared__ u16 Pl[4 * 16 * 64];  // per-wave P [16 q][64 k] u16, XOR-swizzled
  const int t = threadIdx.x;
  const int l = t & 63, w = t >> 6;
  const int g = l >> 4;            // 16-lane group 0..3
  const int qt = blockIdx.x, bh = blockIdx.y;
  const size_t cb = (size_t)bh * 1024 * 128;
  const int q0 = qt*64 + w*16;
  const int lswz = (l & 7) << 4;

  s16x8 qf[4];   // B-frag of Q^T: col q = l&15
#pragma unroll
  for (int dc = 0; dc < 4; ++dc)
    qf[dc] = ldf((const char*)(Qb + cb) + (size_t)(q0 + (l & 15))*256 + dc*64 + (g*16));

  f32x4 o[8];
#pragma unroll
  for (int dc = 0; dc < 8; ++dc) o[dc] = (f32x4){0.f, 0.f, 0.f, 0.f};
  float mrun = -INFINITY, lrun = 0.f;   // per-lane: q = l&15

  const int krow = t >> 4;
  const int kins = (((t & 15) ^ (krow & 7)) << 4);
  const char* gK0 = (const char*)(Kb + cb) + (size_t)krow*256 + kins;
  const int vrow = t >> 3;
  const int vins = (((t & 7) ^ (vrow & 7)) << 4);
  const char* gV0 = (const char*)(Vtb + cb) + (size_t)vrow*2048 + vins;

  auto stage = [&](int kt, int buf) {
    char* kd = Ks + buf*16384 + w*1024;
    char* vd = Vs + buf*16384 + w*1024;
#pragma unroll
    for (int is = 0; is < 4; ++is) {
      gl16(gK0 + (size_t)kt*16384 + (size_t)is*16*256, kd + is*4096);
      gl16(gV0 + (size_t)kt*128 + (size_t)is*32*2048, vd + is*4096);
    }
  };

  char* pwB = (char*)(Pl + w*1024);           // 2KB per wave, row stride 128B
  const int prow = (l & 15);
  const int pkey = (prow & 7) << 4;
  const int pread0 = prow*128 + ((0*64 + g*16) ^ pkey);
  const int pread1 = prow*128 + ((1*64 + g*16) ^ pkey);
  const int srcbase = l & 48;                  // for alpha/lrun cross-layout shfl

  auto qkstep = [&](int kt, int cur) {
    if (kt < 15) { stage(kt + 1, cur ^ 1); WAITVM8(); }
    else         { WAITVM0(); }
    __builtin_amdgcn_sched_barrier(0);
    __builtin_amdgcn_s_barrier();
    const char* Kc = Ks + cur*16384;
    const char* Vc = Vs + cur*16384;
    f32x4 s[4];
#pragma unroll
    for (int kf = 0; kf < 4; ++kf) s[kf] = (f32x4){0.f, 0.f, 0.f, 0.f};
    __builtin_amdgcn_s_setprio(1);
#pragma unroll
    for (int dc = 0; dc < 4; ++dc) {
#pragma unroll
      for (int kf = 0; kf < 4; ++kf) {
        s16x8 kfr = ldf(Kc + (kf*16 + (l & 15))*256 + ((dc*64 + g*16) ^ lswz));
        s[kf] = mfma16(kfr, qf[dc], s[kf]);
      }
    }
    __builtin_amdgcn_s_setprio(0);
    float m01, m23, pmax;
    m01 = fmaxf(fmaxf(s[0][0], s[0][1]), fmaxf(s[0][2], s[0][3]));
    m23 = fmaxf(fmaxf(s[1][0], s[1][1]), fmaxf(s[1][2], s[1][3]));
    pmax = fmaxf(m01, m23);
    m01 = fmaxf(fmaxf(s[2][0], s[2][1]), fmaxf(s[2][2], s[2][3]));
    m23 = fmaxf(fmaxf(s[3][0], s[3][1]), fmaxf(s[3][2], s[3][3]));
    pmax = fmaxf(pmax, fmaxf(m01, m23));
    pmax = fmaxf(pmax, __shfl_xor(pmax, 16));
    pmax = fmaxf(pmax, __shfl_xor(pmax, 32));
    const bool skip = __all(pmax <= mrun + 8.0f);   // defer-max THR=8
    float mnew, alpha;
    if (skip) { mnew = mrun; alpha = 1.0f; }
    else      { mnew = fmaxf(mrun, pmax); alpha = __expf(mrun - mnew); }
    float psum = 0.f;
#pragma unroll
    for (int kf = 0; kf < 4; ++kf) {
#pragma unroll
      for (int r = 0; r < 4; ++r) {
        const float p = __expf(s[kf][r] - mnew);
        s[kf][r] = p;
        psum += p;
      }
    }
    psum += __shfl_xor(psum, 16);
    psum += __shfl_xor(psum, 32);
    lrun = lrun * alpha + psum;
    mrun = mnew;
    if (!skip) {
      float a4[4];
#pragma unroll
      for (int r = 0; r < 4; ++r) a4[r] = __shfl(alpha, srcbase | (g*4 + r));
#pragma unroll
      for (int dc = 0; dc < 8; ++dc)
#pragma unroll
        for (int r = 0; r < 4; ++r) o[dc][r] *= a4[r];
    }
#pragma unroll
    for (int kf = 0; kf < 4; ++kf) {
      uint2 pk;
      pk.x = (unsigned)f2bf(s[kf][0]) | ((unsigned)f2bf(s[kf][1]) << 16);
      pk.y = (unsigned)f2bf(s[kf][2]) | ((unsigned)f2bf(s[kf][3]) << 16);
      *(uint2*)(pwB + prow*128 + ((kf*32 + g*8) ^ pkey)) = pk;
    }
    s16x8 pa[2];
    pa[0] = ldf(pwB + pread0);
    pa[1] = ldf(pwB + pread1);
    __builtin_amdgcn_s_setprio(1);
#pragma unroll
    for (int dc = 0; dc < 8; ++dc) {
#pragma unroll
      for (int c = 0; c < 2; ++c) {
        s16x8 vf = ldf(Vc + (dc*16 + (l & 15))*128 + ((c*64 + g*16) ^ lswz));
        o[dc] = mfma16(pa[c], vf, o[dc]);
      }
    }
    __builtin_amdgcn_s_setprio(0);
    __builtin_amdgcn_s_barrier();
  };

  stage(0, 0);
  for (int kt = 0; kt < 16; kt += 2) {
    qkstep(kt, 0);
    qkstep(kt + 1, 1);
  }

  float linv[4];
#pragma unroll
  for (int r = 0; r < 4; ++r)
    linv[r] = 1.0f / __shfl(lrun, srcbase | (g*4 + r));
#pragma unroll
  for (int r = 0; r < 4; ++r) {
    const int q = q0 + g*4 + r;
#pragma unroll
    for (int dc = 0; dc < 8; ++dc)
      Ob[cb + (size_t)q*128 + dc*16 + (l & 15)] = f2bf(o[dc][r] * linv[r]);
  }
}

// ---------------- output projection (+residual), core DB: grid (32,4,2) ----------
__global__ __launch_bounds__(256) void k_oproj(
    const u16* __restrict__ Ob, const u16* __restrict__ wot,
    const float* __restrict__ x, float* __restrict__ s1)
{
  __shared__ char As[2*16384], Bs[2*16384];
  const int t = threadIdx.x;
  const int mt = blockIdx.x, nt = blockIdx.y, half = blockIdx.z;
  const int rowA = t >> 3;
  const int insw = (((t & 7) ^ (rowA & 7)) << 4);
  const int b = mt >> 3;
  const char* gA = (const char*)Ob + ((size_t)(b*8)*1024 + (mt & 7)*128 + rowA)*256
                   + half*128 + insw;
  const char* gB = (const char*)(wot + (size_t)half*262144) + (size_t)(nt*128 + rowA)*1024 + insw;
  f32x4 acc[4][4] = {};
  gemm_core_db(gA, 262144, 32L*256, gB, 128, 32L*1024, 8, As, Bs, t, acc);
  const int l = t & 63, w = t >> 6, wr = w >> 1, wc = w & 1;
#pragma unroll
  for (int mi = 0; mi < 4; ++mi)
#pragma unroll
    for (int r = 0; r < 4; ++r) {
      const int gr = mt*128 + wr*64 + mi*16 + ((l >> 4) << 2) + r;
#pragma unroll
      for (int nj = 0; nj < 4; ++nj) {
        const int col = half*512 + nt*128 + wc*64 + nj*16 + (l & 15);
        const size_t idx = (size_t)gr*1024 + col;
        s1[idx] = acc[mi][nj][r] + x[idx];
      }
    }
}

// ---------------- FFN1 (bias+ReLU), core1: grid (32,16,2) ----------------
__global__ __launch_bounds__(256) void k_ffn1(
    const u16* __restrict__ x1b, const u16* __restrict__ w1b,
    const float* __restrict__ b1c, const float* __restrict__ b1p,
    u16* __restrict__ hb)
{
  __shared__ char As[16384], Bs[16384];
  const int t = threadIdx.x;
  const int mt = blockIdx.x, nt = blockIdx.y, half = blockIdx.z;
  const int rowA = t >> 3;
  const int insw = (((t & 7) ^ (rowA & 7)) << 4);
  const char* gA = (const char*)x1b + half*1024 + (size_t)(mt*128 + rowA)*2048 + insw;
  const char* gB = (const char*)w1b + (size_t)half*2097152 + (size_t)(nt*128 + rowA)*1024 + insw;
  const float* bb = half ? b1p : b1c;
  f32x4 acc[4][4] = {};
  gemm_core(gA, 128, 32L*2048, gB, 128, 32L*1024, 8, As, Bs, t, acc);
  const int l = t & 63, w = t >> 6, wr = w >> 1, wc = w & 1;
#pragma unroll
  for (int mi = 0; mi < 4; ++mi)
#pragma unroll
    for (int r = 0; r < 4; ++r) {
      const int gr = mt*128 + wr*64 + mi*16 + ((l >> 4) << 2) + r;
#pragma unroll
      for (int nj = 0; nj < 4; ++nj) {
        const int n = nt*128 + wc*64 + nj*16 + (l & 15);
        hb[(size_t)gr*4096 + half*2048 + n] = f2bf(fmaxf(acc[mi][nj][r] + bb[n], 0.f));
      }
    }
}

// ---------------- FFN2 (bias + bf16 residual), core DB: grid (32,4,2) ---------
__global__ __launch_bounds__(256) void k_ffn2(
    const u16* __restrict__ hb, const u16* __restrict__ w2b,
    const float* __restrict__ b2c, const float* __restrict__ b2p,
    const u16* __restrict__ x1b, float* __restrict__ s2)
{
  __shared__ char As[2*16384], Bs[2*16384];
  const int t = threadIdx.x;
  const int mt = blockIdx.x, nt = blockIdx.y, half = blockIdx.z;
  const int rowA = t >> 3;
  const int insw = (((t & 7) ^ (rowA & 7)) << 4);
  const char* gA = (const char*)hb + (size_t)(mt*128 + rowA)*8192 + half*4096 + insw;
  const char* gB = (const char*)w2b + (size_t)half*2097152 + (size_t)(nt*128 + rowA)*4096 + insw;
  const float* bb = half ? b2p : b2c;
  f32x4 acc[4][4] = {};
  gemm_core_db(gA, 128, 32L*8192, gB, 128, 32L*4096, 32, As, Bs, t, acc);
  const int l = t & 63, w = t >> 6, wr = w >> 1, wc = w & 1;
#pragma unroll
  for (int mi = 0; mi < 4; ++mi)
#pragma unroll
    for (int r = 0; r < 4; ++r) {
      const int gr = mt*128 + wr*64 + mi*16 + ((l >> 4) << 2) + r;
#pragma unroll
      for (int nj = 0; nj < 4; ++nj) {
        const int nloc = nt*128 + wc*64 + nj*16 + (l & 15);
        const size_t idx = (size_t)gr*1024 + half*512 + nloc;
        s2[idx] = acc[mi][nj][r] + bb[nloc] + bf2f(x1b[idx]);
      }
    }
}

// ---------------- LayerNorm: wave-per-row, 4 rows/block, grid 1024 ----------------
__global__ __launch_bounds__(256) void k_ln4(
    const float* __restrict__ in, const float* __restrict__ g,
    const float* __restrict__ be, float* __restrict__ outf, u16* __restrict__ outb)
{
  const int t = threadIdx.x;
  const int l = t & 63;
  const int row = blockIdx.x*4 + (t >> 6);
  const float4* src = reinterpret_cast<const float4*>(in + (size_t)row*1024);
  float4 v[4];
  float s = 0.f, ss = 0.f;
#pragma unroll
  for (int j = 0; j < 4; ++j) {
    v[j] = src[l + 64*j];
    s  += v[j].x + v[j].y + v[j].z + v[j].w;
    ss += v[j].x*v[j].x + v[j].y*v[j].y + v[j].z*v[j].z + v[j].w*v[j].w;
  }
#pragma unroll
  for (int off = 1; off < 64; off <<= 1) {
    s  += __shfl_xor(s, off);
    ss += __shfl_xor(ss, off);
  }
  const float mu = s * (1.f/1024.f);
  const float var = ss * (1.f/1024.f) - mu*mu;
  const float rs = rsqrtf(var + 1e-5f);
#pragma unroll
  for (int j = 0; j < 4; ++j) {
    const int c4 = l + 64*j;
    float4 gv = reinterpret_cast<const float4*>(g)[c4];
    float4 bv = reinterpret_cast<const float4*>(be)[c4];
    float4 ov;
    ov.x = (v[j].x - mu)*rs*gv.x + bv.x;
    ov.y = (v[j].y - mu)*rs*gv.y + bv.y;
    ov.z = (v[j].z - mu)*rs*gv.z + bv.z;
    ov.w = (v[j].w - mu)*rs*gv.w + bv.w;
    if (outf)
      reinterpret_cast<float4*>(outf + (size_t)row*1024)[c4] = ov;
    if (outb) {
      uint2 pk;
      pk.x = (unsigned)f2bf(ov.x) | ((unsigned)f2bf(ov.y) << 16);
      pk.y = (unsigned)f2bf(ov.z) | ((unsigned)f2bf(ov.w) << 16);
      reinterpret_cast<uint2*>(outb + (size_t)row*1024)[c4] = pk;
    }
  }
}

}  // namespace

extern "C" void kernel_launch(void* const* d_in, const int* in_sizes, int n_in,
                              void* d_out, int out_size, void* d_ws, size_t ws_size,
                              hipStream_t stream)
{
  (void)in_sizes; (void)n_in; (void)out_size; (void)ws_size;
  const float* x      = (const float*)d_in[0];
  const float* wqkv_c = (const float*)d_in[2];
  const float* wqkv_p = (const float*)d_in[3];
  const float* wo_c   = (const float*)d_in[4];
  const float* wo_p   = (const float*)d_in[5];
  const float* w1_c   = (const float*)d_in[6];
  const float* b1_c   = (const float*)d_in[7];
  const float* w1_p   = (const float*)d_in[8];
  const float* b1_p   = (const float*)d_in[9];
  const float* w2_c   = (const float*)d_in[10];
  const float* b2_c   = (const float*)d_in[11];
  const float* w2_p   = (const float*)d_in[12];
  const float* b2_p   = (const float*)d_in[13];
  const float* ln1_g  = (const float*)d_in[14];
  const float* ln1_b  = (const float*)d_in[15];
  const float* ln2_g  = (const float*)d_in[16];
  const float* ln2_b  = (const float*)d_in[17];

  // workspace layout (bytes)
  char* W = (char*)d_ws;
  u16*   xb  = (u16*)(W);                      // 8MB; Ob aliases after QKV
  u16*   Ob  = xb;
  u16*   Qb  = (u16*)(W + (8u  << 20));        // 8MB [b,h,tok,128]
  u16*   Kb  = (u16*)(W + (16u << 20));        // 8MB
  u16*   Vtb = (u16*)(W + (24u << 20));        // 8MB [b,h,d,tok]
  u16*   Bqt = (u16*)(W + (32u << 20));        // 3MB [2][1536][512]
  u16*   wot = (u16*)(W + (35u << 20));        // 1MB [2][512][512]
  u16*   w1b = (u16*)(W + (36u << 20));        // 4MB [2][2048][512]
  u16*   w2b = (u16*)(W + (40u << 20));        // 4MB [2][512][2048]
  float* s1  = (float*)(W + (44u << 20));      // 16MB fp32 (attn+res, then ffn+res)
  u16*   x1b = (u16*)(W + (60u << 20));        // 8MB bf16 LN1 output
  u16*   hb  = (u16*)(W + (68u << 20));        // 32MB [4096][4096] (half-interleaved)
  float* out = (float*)d_out;

  k_prep <<<10240, 256, 0, stream>>>(x, w1_c, w1_p, w2_c, w2_p,
                                     wo_c, wo_p, wqkv_c, wqkv_p,
                                     xb, w1b, w2b, wot, Bqt);
  k_qkv_g<<<dim3(32, 12, 2), 256, 0, stream>>>(xb, Bqt, Qb, Kb, Vtb);
  k_attn <<<dim3(16, 32),    256, 0, stream>>>(Qb, Kb, Vtb, Ob);
  k_oproj<<<dim3(32, 4, 2),  256, 0, stream>>>(Ob, wot, x, s1);
  k_ln4  <<<1024,            256, 0, stream>>>(s1, ln1_g, ln1_b, nullptr, x1b);
  k_ffn1 <<<dim3(32, 16, 2), 256, 0, stream>>>(x1b, w1b, b1_c, b1_p, hb);
  k_ffn2 <<<dim3(32, 4, 2),  256, 0, stream>>>(hb, w2b, b2_c, b2_p, x1b, s1);
  k_ln4  <<<1024,            256, 0, stream>>>(s1, ln2_g, ln2_b, out, nullptr);
}

// Round 11
// 265.181 us; speedup vs baseline: 1.1506x; 1.0038x over previous
//
#include <hip/hip_runtime.h>
#include <math.h>

// PartitionedTransformerEncoderLayer on MI355X — round 11.
// vs round 10: oproj and ffn2 (the two 1-block/CU kernels, proven latency-bound:
// MfmaUtil 14%, VALU 12%, occ 9.7%) get K-split x2 -> grid.z=4, 512 blocks =
// 2 blocks/CU (TLP, the mechanism that makes qkv/ffn1 fast). Partial sums go to
// two fp32 buffers; the adjacent LayerNorm folds partial0+partial1+residual
// (+bias for ffn2). attn/prep/qkv/ffn1/cores untouched.

namespace {

typedef unsigned short u16;
typedef __attribute__((ext_vector_type(8))) short s16x8;
typedef __attribute__((ext_vector_type(4))) float f32x4;

__device__ inline u16 f2bf(float f) {
  union { float f; unsigned u; } c; c.f = f;
  unsigned u = c.u;
  return (u16)((u + 0x7fffu + ((u >> 16) & 1u)) >> 16);
}

__device__ inline float bf2f(u16 v) {
  union { unsigned u; float f; } c; c.u = ((unsigned)v) << 16; return c.f;
}

__device__ inline void gl16(const void* g, void* l) {
  __builtin_amdgcn_global_load_lds(
      (const __attribute__((address_space(1))) unsigned int*)g,
      (__attribute__((address_space(3))) unsigned int*)l, 16, 0, 0);
}

__device__ inline s16x8 ldf(const void* p) { return *(const s16x8*)p; }

__device__ inline f32x4 mfma16(s16x8 a, s16x8 b, f32x4 c) {
  return __builtin_amdgcn_mfma_f32_16x16x32_bf16(a, b, c, 0, 0, 0);
}

#define WAITVM8() asm volatile("s_waitcnt vmcnt(8)" ::: "memory")
#define WAITVM0() asm volatile("s_waitcnt vmcnt(0)" ::: "memory")

// ---------------- GEMM core 1: 128x128, 4 waves, wave-tile 64x64 ----------------
__device__ inline void gemm_core(const char* gA, long stepA, long rs32A,
                                 const char* gB, long stepB, long rs32B,
                                 int ksteps, char* AsB, char* BsB, int t,
                                 f32x4 acc[4][4])
{
  const int l = t & 63;
  const int w = t >> 6;
  const int wr = w >> 1, wc = w & 1;
  const int lswz = (l & 7) << 4;
  const int wofs = w * 1024;
  int aoff[4][2], boff[4][2];
#pragma unroll
  for (int mi = 0; mi < 4; ++mi)
#pragma unroll
    for (int c = 0; c < 2; ++c) {
      aoff[mi][c] = (wr*64 + mi*16 + (l & 15))*128 + ((c*64 + ((l >> 4)*16)) ^ lswz);
      boff[mi][c] = (wc*64 + mi*16 + (l & 15))*128 + ((c*64 + ((l >> 4)*16)) ^ lswz);
    }
  for (int ks = 0; ks < ksteps; ++ks) {
#pragma unroll
    for (int is = 0; is < 4; ++is) {
      gl16(gA + is*rs32A, AsB + is*4096 + wofs);
      gl16(gB + is*rs32B, BsB + is*4096 + wofs);
    }
    gA += stepA; gB += stepB;
    __syncthreads();
    s16x8 af[4][2], bf[4][2];
#pragma unroll
    for (int mi = 0; mi < 4; ++mi)
#pragma unroll
      for (int c = 0; c < 2; ++c) {
        af[mi][c] = ldf(AsB + aoff[mi][c]);
        bf[mi][c] = ldf(BsB + boff[mi][c]);
      }
#pragma unroll
    for (int mi = 0; mi < 4; ++mi)
#pragma unroll
      for (int nj = 0; nj < 4; ++nj)
#pragma unroll
        for (int c = 0; c < 2; ++c)
          acc[mi][nj] = mfma16(af[mi][c], bf[nj][c], acc[mi][nj]);
    __syncthreads();
  }
}

// ---------------- GEMM core DB: 128x128, double-buffered, stage-ahead ----------------
__device__ inline void gemm_core_db(const char* gA, long stepA, long rs32A,
                                    const char* gB, long stepB, long rs32B,
                                    int ksteps, char* AsB, char* BsB, int t,
                                    f32x4 acc[4][4])
{
  const int l = t & 63;
  const int w = t >> 6;
  const int wr = w >> 1, wc = w & 1;
  const int lswz = (l & 7) << 4;
  const int wofs = w * 1024;
  int aoff[4][2], boff[4][2];
#pragma unroll
  for (int mi = 0; mi < 4; ++mi)
#pragma unroll
    for (int c = 0; c < 2; ++c) {
      aoff[mi][c] = (wr*64 + mi*16 + (l & 15))*128 + ((c*64 + ((l >> 4)*16)) ^ lswz);
      boff[mi][c] = (wc*64 + mi*16 + (l & 15))*128 + ((c*64 + ((l >> 4)*16)) ^ lswz);
    }
  auto stage = [&](int ks, int buf) {
    const char* A = gA + (long)ks*stepA;
    const char* B = gB + (long)ks*stepB;
    char* ad = AsB + buf*16384 + wofs;
    char* bd = BsB + buf*16384 + wofs;
#pragma unroll
    for (int is = 0; is < 4; ++is) {
      gl16(A + is*rs32A, ad + is*4096);
      gl16(B + is*rs32B, bd + is*4096);
    }
  };
  stage(0, 0);
  for (int ks = 0; ks < ksteps; ++ks) {
    const int cur = ks & 1;
    if (ks + 1 < ksteps) { stage(ks + 1, cur ^ 1); WAITVM8(); }
    else                 { WAITVM0(); }
    __builtin_amdgcn_sched_barrier(0);
    __builtin_amdgcn_s_barrier();
    const char* Ac = AsB + cur*16384;
    const char* Bc = BsB + cur*16384;
    s16x8 af[4][2], bf[4][2];
#pragma unroll
    for (int mi = 0; mi < 4; ++mi)
#pragma unroll
      for (int c = 0; c < 2; ++c) {
        af[mi][c] = ldf(Ac + aoff[mi][c]);
        bf[mi][c] = ldf(Bc + boff[mi][c]);
      }
    __builtin_amdgcn_s_setprio(1);
#pragma unroll
    for (int mi = 0; mi < 4; ++mi)
#pragma unroll
      for (int nj = 0; nj < 4; ++nj)
#pragma unroll
        for (int c = 0; c < 2; ++c)
          acc[mi][nj] = mfma16(af[mi][c], bf[nj][c], acc[mi][nj]);
    __builtin_amdgcn_s_setprio(0);
    __builtin_amdgcn_s_barrier();
  }
}

// ---------------- merged prep: cast x, cast FFN weights, transpose wo, wqkv ---------
__global__ __launch_bounds__(256) void k_prep(
    const float* __restrict__ x,
    const float* __restrict__ w1c, const float* __restrict__ w1p,
    const float* __restrict__ w2c, const float* __restrict__ w2p,
    const float* __restrict__ woc, const float* __restrict__ wop,
    const float* __restrict__ wqc, const float* __restrict__ wqp,
    u16* __restrict__ xb, u16* __restrict__ w1b, u16* __restrict__ w2b,
    u16* __restrict__ wot, u16* __restrict__ Bqt)
{
  __shared__ float tile[32][33];
  const int bid = blockIdx.x;
  const int t = threadIdx.x;
  if (bid < 4096) {
    const int i = bid*256 + t;
    float4 v = reinterpret_cast<const float4*>(x)[i];
    uint2 pk;
    pk.x = (unsigned)f2bf(v.x) | ((unsigned)f2bf(v.y) << 16);
    pk.y = (unsigned)f2bf(v.z) | ((unsigned)f2bf(v.w) << 16);
    reinterpret_cast<uint2*>(xb)[i] = pk;
  } else if (bid < 8192) {
    const int j = bid - 4096;
    const float* src; u16* dst;
    switch (j >> 10) {
      case 0:  src = w1c; dst = w1b;            break;
      case 1:  src = w1p; dst = w1b + 1048576;  break;
      case 2:  src = w2c; dst = w2b;            break;
      default: src = w2p; dst = w2b + 1048576;  break;
    }
    const int i = (j & 1023)*256 + t;
    float4 v = reinterpret_cast<const float4*>(src)[i];
    uint2 pk;
    pk.x = (unsigned)f2bf(v.x) | ((unsigned)f2bf(v.y) << 16);
    pk.y = (unsigned)f2bf(v.z) | ((unsigned)f2bf(v.w) << 16);
    reinterpret_cast<uint2*>(dst)[i] = pk;
  } else if (bid < 8704) {
    const int j = bid - 8192;
    const int half = j >> 8, rem = j & 255;
    const int r0 = (rem >> 4) * 32, c0 = (rem & 15) * 32;
    const float* in = half ? wop : woc;
    u16* o = wot + (size_t)half * 512 * 512;
    const int tx = t & 31, ty = t >> 5;
#pragma unroll
    for (int jj = 0; jj < 4; ++jj)
      tile[ty + 8*jj][tx] = in[(size_t)(r0 + ty + 8*jj)*512 + c0 + tx];
    __syncthreads();
#pragma unroll
    for (int jj = 0; jj < 4; ++jj)
      o[(size_t)(c0 + ty + 8*jj)*512 + r0 + tx] = f2bf(tile[tx][ty + 8*jj]);
  } else {
    const int j = bid - 8704;
    const int z = j / 96, rem = j - z*96;
    const int by = rem / 6, bx = rem - by*6;
    const int half = z >> 3, h = z & 7;
    const float* in = (half ? wqp : wqc) + (size_t)h * 98304;   // [f=512][ca=192]
    u16* o = Bqt + (size_t)half * 786432 + (size_t)h * 98304;   // [ca=192][f=512]
    const int r0 = by * 32, c0 = bx * 32;
    const int tx = t & 31, ty = t >> 5;
#pragma unroll
    for (int jj = 0; jj < 4; ++jj)
      tile[ty + 8*jj][tx] = in[(size_t)(r0 + ty + 8*jj)*192 + c0 + tx];
    __syncthreads();
#pragma unroll
    for (int jj = 0; jj < 4; ++jj)
      o[(size_t)(c0 + ty + 8*jj)*512 + r0 + tx] = f2bf(tile[tx][ty + 8*jj]);
  }
}

// ---------------- QKV projection GEMM (core1) ----------------
__global__ __launch_bounds__(256) void k_qkv_g(
    const u16* __restrict__ xb, const u16* __restrict__ Bqt,
    u16* __restrict__ Qb, u16* __restrict__ Kb, u16* __restrict__ Vtb)
{
  __shared__ char As[16384], Bs[16384];
  const int t = threadIdx.x;
  const int mt = blockIdx.x, nt = blockIdx.y, half = blockIdx.z;
  const int rowA = t >> 3;
  const int insw = (((t & 7) ^ (rowA & 7)) << 4);
  const char* gA = (const char*)xb + half*1024 + (size_t)(mt*128 + rowA)*2048 + insw;
  const char* gB = (const char*)(Bqt + (size_t)half*786432) + (size_t)(nt*128 + rowA)*1024 + insw;
  f32x4 acc[4][4] = {};
  gemm_core(gA, 128, 32L*2048, gB, 128, 32L*1024, 8, As, Bs, t, acc);
  const int l = t & 63, w = t >> 6, wr = w >> 1, wc = w & 1;
#pragma unroll
  for (int nj = 0; nj < 4; ++nj) {
    const int gc = nt*128 + wc*64 + nj*16 + (l & 15);
    const int h = gc / 192, rem = gc - h*192;
    const int cc = rem >> 6, a = rem & 63;
#pragma unroll
    for (int mi = 0; mi < 4; ++mi) {
#pragma unroll
      for (int r = 0; r < 4; ++r) {
        const int gr = mt*128 + wr*64 + mi*16 + ((l >> 4) << 2) + r;
        const int b = gr >> 10, tok = gr & 1023;
        const float v = acc[mi][nj][r];
        if (cc == 0)
          Qb[((size_t)((b*8 + h)*1024 + tok))*128 + half*64 + a] =
              f2bf(v * 0.08838834764831843f);
        else if (cc == 1)
          Kb[((size_t)((b*8 + h)*1024 + tok))*128 + half*64 + a] = f2bf(v);
        else
          Vtb[((size_t)((b*8 + h)*128 + half*64 + a))*1024 + tok] = f2bf(v);
      }
    }
  }
}

// ---------------- MFMA flash attention (swapped QK^T, in-lane softmax) ----------------
__global__ __launch_bounds__(256) void k_attn(
    const u16* __restrict__ Qb, const u16* __restrict__ Kb,
    const u16* __restrict__ Vtb, u16* __restrict__ Ob)
{
  __shared__ char Ks[2 * 16384];
  __shared__ char Vs[2 * 16384];
  __shared__ u16 Pl[4 * 16 * 64];
  const int t = threadIdx.x;
  const int l = t & 63, w = t >> 6;
  const int g = l >> 4;
  const int qt = blockIdx.x, bh = blockIdx.y;
  const size_t cb = (size_t)bh * 1024 * 128;
  const int q0 = qt*64 + w*16;
  const int lswz = (l & 7) << 4;

  s16x8 qf[4];
#pragma unroll
  for (int dc = 0; dc < 4; ++dc)
    qf[dc] = ldf((const char*)(Qb + cb) + (size_t)(q0 + (l & 15))*256 + dc*64 + (g*16));

  f32x4 o[8];
#pragma unroll
  for (int dc = 0; dc < 8; ++dc) o[dc] = (f32x4){0.f, 0.f, 0.f, 0.f};
  float mrun = -INFINITY, lrun = 0.f;

  const int krow = t >> 4;
  const int kins = (((t & 15) ^ (krow & 7)) << 4);
  const char* gK0 = (const char*)(Kb + cb) + (size_t)krow*256 + kins;
  const int vrow = t >> 3;
  const int vins = (((t & 7) ^ (vrow & 7)) << 4);
  const char* gV0 = (const char*)(Vtb + cb) + (size_t)vrow*2048 + vins;

  auto stage = [&](int kt, int buf) {
    char* kd = Ks + buf*16384 + w*1024;
    char* vd = Vs + buf*16384 + w*1024;
#pragma unroll
    for (int is = 0; is < 4; ++is) {
      gl16(gK0 + (size_t)kt*16384 + (size_t)is*16*256, kd + is*4096);
      gl16(gV0 + (size_t)kt*128 + (size_t)is*32*2048, vd + is*4096);
    }
  };

  char* pwB = (char*)(Pl + w*1024);
  const int prow = (l & 15);
  const int pkey = (prow & 7) << 4;
  const int pread0 = prow*128 + ((0*64 + g*16) ^ pkey);
  const int pread1 = prow*128 + ((1*64 + g*16) ^ pkey);
  const int srcbase = l & 48;

  auto qkstep = [&](int kt, int cur) {
    if (kt < 15) { stage(kt + 1, cur ^ 1); WAITVM8(); }
    else         { WAITVM0(); }
    __builtin_amdgcn_sched_barrier(0);
    __builtin_amdgcn_s_barrier();
    const char* Kc = Ks + cur*16384;
    const char* Vc = Vs + cur*16384;
    f32x4 s[4];
#pragma unroll
    for (int kf = 0; kf < 4; ++kf) s[kf] = (f32x4){0.f, 0.f, 0.f, 0.f};
    __builtin_amdgcn_s_setprio(1);
#pragma unroll
    for (int dc = 0; dc < 4; ++dc) {
#pragma unroll
      for (int kf = 0; kf < 4; ++kf) {
        s16x8 kfr = ldf(Kc + (kf*16 + (l & 15))*256 + ((dc*64 + g*16) ^ lswz));
        s[kf] = mfma16(kfr, qf[dc], s[kf]);
      }
    }
    __builtin_amdgcn_s_setprio(0);
    float m01, m23, pmax;
    m01 = fmaxf(fmaxf(s[0][0], s[0][1]), fmaxf(s[0][2], s[0][3]));
    m23 = fmaxf(fmaxf(s[1][0], s[1][1]), fmaxf(s[1][2], s[1][3]));
    pmax = fmaxf(m01, m23);
    m01 = fmaxf(fmaxf(s[2][0], s[2][1]), fmaxf(s[2][2], s[2][3]));
    m23 = fmaxf(fmaxf(s[3][0], s[3][1]), fmaxf(s[3][2], s[3][3]));
    pmax = fmaxf(pmax, fmaxf(m01, m23));
    pmax = fmaxf(pmax, __shfl_xor(pmax, 16));
    pmax = fmaxf(pmax, __shfl_xor(pmax, 32));
    const bool skip = __all(pmax <= mrun + 8.0f);
    float mnew, alpha;
    if (skip) { mnew = mrun; alpha = 1.0f; }
    else      { mnew = fmaxf(mrun, pmax); alpha = __expf(mrun - mnew); }
    float psum = 0.f;
#pragma unroll
    for (int kf = 0; kf < 4; ++kf) {
#pragma unroll
      for (int r = 0; r < 4; ++r) {
        const float p = __expf(s[kf][r] - mnew);
        s[kf][r] = p;
        psum += p;
      }
    }
    psum += __shfl_xor(psum, 16);
    psum += __shfl_xor(psum, 32);
    lrun = lrun * alpha + psum;
    mrun = mnew;
    if (!skip) {
      float a4[4];
#pragma unroll
      for (int r = 0; r < 4; ++r) a4[r] = __shfl(alpha, srcbase | (g*4 + r));
#pragma unroll
      for (int dc = 0; dc < 8; ++dc)
#pragma unroll
        for (int r = 0; r < 4; ++r) o[dc][r] *= a4[r];
    }
#pragma unroll
    for (int kf = 0; kf < 4; ++kf) {
      uint2 pk;
      pk.x = (unsigned)f2bf(s[kf][0]) | ((unsigned)f2bf(s[kf][1]) << 16);
      pk.y = (unsigned)f2bf(s[kf][2]) | ((unsigned)f2bf(s[kf][3]) << 16);
      *(uint2*)(pwB + prow*128 + ((kf*32 + g*8) ^ pkey)) = pk;
    }
    s16x8 pa[2];
    pa[0] = ldf(pwB + pread0);
    pa[1] = ldf(pwB + pread1);
    __builtin_amdgcn_s_setprio(1);
#pragma unroll
    for (int dc = 0; dc < 8; ++dc) {
#pragma unroll
      for (int c = 0; c < 2; ++c) {
        s16x8 vf = ldf(Vc + (dc*16 + (l & 15))*128 + ((c*64 + g*16) ^ lswz));
        o[dc] = mfma16(pa[c], vf, o[dc]);
      }
    }
    __builtin_amdgcn_s_setprio(0);
    __builtin_amdgcn_s_barrier();
  };

  stage(0, 0);
  for (int kt = 0; kt < 16; kt += 2) {
    qkstep(kt, 0);
    qkstep(kt + 1, 1);
  }

  float linv[4];
#pragma unroll
  for (int r = 0; r < 4; ++r)
    linv[r] = 1.0f / __shfl(lrun, srcbase | (g*4 + r));
#pragma unroll
  for (int r = 0; r < 4; ++r) {
    const int q = q0 + g*4 + r;
#pragma unroll
    for (int dc = 0; dc < 8; ++dc)
      Ob[cb + (size_t)q*128 + dc*16 + (l & 15)] = f2bf(o[dc][r] * linv[r]);
  }
}

// ------- output projection, K-split x2: grid (32,4,4), z = half*2+kk -------
// Partial (no residual) -> sp. kk selects heads 0-3 / 4-7.
__global__ __launch_bounds__(256) void k_oproj(
    const u16* __restrict__ Ob, const u16* __restrict__ wot,
    float* __restrict__ spA, float* __restrict__ spB)
{
  __shared__ char As[2*16384], Bs[2*16384];
  const int t = threadIdx.x;
  const int mt = blockIdx.x, nt = blockIdx.y;
  const int half = blockIdx.z >> 1, kk = blockIdx.z & 1;
  const int rowA = t >> 3;
  const int insw = (((t & 7) ^ (rowA & 7)) << 4);
  const int b = mt >> 3;
  const char* gA = (const char*)Ob + ((size_t)(b*8 + kk*4)*1024 + (mt & 7)*128 + rowA)*256
                   + half*128 + insw;
  const char* gB = (const char*)(wot + (size_t)half*262144)
                   + (size_t)(nt*128 + rowA)*1024 + kk*512 + insw;
  f32x4 acc[4][4] = {};
  gemm_core_db(gA, 262144, 32L*256, gB, 128, 32L*1024, 4, As, Bs, t, acc);
  float* sp = kk ? spB : spA;
  const int l = t & 63, w = t >> 6, wr = w >> 1, wc = w & 1;
#pragma unroll
  for (int mi = 0; mi < 4; ++mi)
#pragma unroll
    for (int r = 0; r < 4; ++r) {
      const int gr = mt*128 + wr*64 + mi*16 + ((l >> 4) << 2) + r;
#pragma unroll
      for (int nj = 0; nj < 4; ++nj) {
        const int col = half*512 + nt*128 + wc*64 + nj*16 + (l & 15);
        sp[(size_t)gr*1024 + col] = acc[mi][nj][r];
      }
    }
}

// ---------------- FFN1 (bias+ReLU), core1: grid (32,16,2) ----------------
__global__ __launch_bounds__(256) void k_ffn1(
    const u16* __restrict__ x1b, const u16* __restrict__ w1b,
    const float* __restrict__ b1c, const float* __restrict__ b1p,
    u16* __restrict__ hb)
{
  __shared__ char As[16384], Bs[16384];
  const int t = threadIdx.x;
  const int mt = blockIdx.x, nt = blockIdx.y, half = blockIdx.z;
  const int rowA = t >> 3;
  const int insw = (((t & 7) ^ (rowA & 7)) << 4);
  const char* gA = (const char*)x1b + half*1024 + (size_t)(mt*128 + rowA)*2048 + insw;
  const char* gB = (const char*)w1b + (size_t)half*2097152 + (size_t)(nt*128 + rowA)*1024 + insw;
  const float* bb = half ? b1p : b1c;
  f32x4 acc[4][4] = {};
  gemm_core(gA, 128, 32L*2048, gB, 128, 32L*1024, 8, As, Bs, t, acc);
  const int l = t & 63, w = t >> 6, wr = w >> 1, wc = w & 1;
#pragma unroll
  for (int mi = 0; mi < 4; ++mi)
#pragma unroll
    for (int r = 0; r < 4; ++r) {
      const int gr = mt*128 + wr*64 + mi*16 + ((l >> 4) << 2) + r;
#pragma unroll
      for (int nj = 0; nj < 4; ++nj) {
        const int n = nt*128 + wc*64 + nj*16 + (l & 15);
        hb[(size_t)gr*4096 + half*2048 + n] = f2bf(fmaxf(acc[mi][nj][r] + bb[n], 0.f));
      }
    }
}

// ------- FFN2, K-split x2: grid (32,4,4), z = half*2+kk. Partial -> sp -------
__global__ __launch_bounds__(256) void k_ffn2(
    const u16* __restrict__ hb, const u16* __restrict__ w2b,
    float* __restrict__ spA, float* __restrict__ spB)
{
  __shared__ char As[2*16384], Bs[2*16384];
  const int t = threadIdx.x;
  const int mt = blockIdx.x, nt = blockIdx.y;
  const int half = blockIdx.z >> 1, kk = blockIdx.z & 1;
  const int rowA = t >> 3;
  const int insw = (((t & 7) ^ (rowA & 7)) << 4);
  const char* gA = (const char*)hb + (size_t)(mt*128 + rowA)*8192 + half*4096
                   + kk*2048 + insw;
  const char* gB = (const char*)w2b + (size_t)half*2097152
                   + (size_t)(nt*128 + rowA)*4096 + kk*2048 + insw;
  f32x4 acc[4][4] = {};
  gemm_core_db(gA, 128, 32L*8192, gB, 128, 32L*4096, 16, As, Bs, t, acc);
  float* sp = kk ? spB : spA;
  const int l = t & 63, w = t >> 6, wr = w >> 1, wc = w & 1;
#pragma unroll
  for (int mi = 0; mi < 4; ++mi)
#pragma unroll
    for (int r = 0; r < 4; ++r) {
      const int gr = mt*128 + wr*64 + mi*16 + ((l >> 4) << 2) + r;
#pragma unroll
      for (int nj = 0; nj < 4; ++nj) {
        const int col = half*512 + nt*128 + wc*64 + nj*16 + (l & 15);
        sp[(size_t)gr*1024 + col] = acc[mi][nj][r];
      }
    }
}

// -------- LayerNorm over (a + b [+ xf] [+ bf16 xr] [+ bias]) — wave/row --------
// bias: cols 0-511 from bc, 512-1023 from bp (both null to disable).
__global__ __launch_bounds__(256) void k_lnsum(
    const float* __restrict__ a, const float* __restrict__ b,
    const float* __restrict__ xf, const u16* __restrict__ xr,
    const float* __restrict__ bc, const float* __restrict__ bp,
    const float* __restrict__ g, const float* __restrict__ be,
    float* __restrict__ outf, u16* __restrict__ outb)
{
  const int t = threadIdx.x;
  const int l = t & 63;
  const int row = blockIdx.x*4 + (t >> 6);
  const size_t rbase = (size_t)row*1024;
  float4 v[4];
  float s = 0.f, ss = 0.f;
#pragma unroll
  for (int j = 0; j < 4; ++j) {
    const int c4 = l + 64*j;
    float4 av = reinterpret_cast<const float4*>(a + rbase)[c4];
    float4 bv = reinterpret_cast<const float4*>(b + rbase)[c4];
    av.x += bv.x; av.y += bv.y; av.z += bv.z; av.w += bv.w;
    if (xf) {
      float4 xv = reinterpret_cast<const float4*>(xf + rbase)[c4];
      av.x += xv.x; av.y += xv.y; av.z += xv.z; av.w += xv.w;
    }
    if (xr) {
      uint2 pk = reinterpret_cast<const uint2*>(xr + rbase)[c4];
      av.x += bf2f((u16)(pk.x & 0xffff));
      av.y += bf2f((u16)(pk.x >> 16));
      av.z += bf2f((u16)(pk.y & 0xffff));
      av.w += bf2f((u16)(pk.y >> 16));
    }
    if (bc) {
      const float4 bbv = (j < 2) ? reinterpret_cast<const float4*>(bc)[c4]
                                 : reinterpret_cast<const float4*>(bp)[c4 - 128];
      av.x += bbv.x; av.y += bbv.y; av.z += bbv.z; av.w += bbv.w;
    }
    v[j] = av;
    s  += av.x + av.y + av.z + av.w;
    ss += av.x*av.x + av.y*av.y + av.z*av.z + av.w*av.w;
  }
#pragma unroll
  for (int off = 1; off < 64; off <<= 1) {
    s  += __shfl_xor(s, off);
    ss += __shfl_xor(ss, off);
  }
  const float mu = s * (1.f/1024.f);
  const float var = ss * (1.f/1024.f) - mu*mu;
  const float rs = rsqrtf(var + 1e-5f);
#pragma unroll
  for (int j = 0; j < 4; ++j) {
    const int c4 = l + 64*j;
    float4 gv = reinterpret_cast<const float4*>(g)[c4];
    float4 bv = reinterpret_cast<const float4*>(be)[c4];
    float4 ov;
    ov.x = (v[j].x - mu)*rs*gv.x + bv.x;
    ov.y = (v[j].y - mu)*rs*gv.y + bv.y;
    ov.z = (v[j].z - mu)*rs*gv.z + bv.z;
    ov.w = (v[j].w - mu)*rs*gv.w + bv.w;
    if (outf)
      reinterpret_cast<float4*>(outf + rbase)[c4] = ov;
    if (outb) {
      uint2 pk;
      pk.x = (unsigned)f2bf(ov.x) | ((unsigned)f2bf(ov.y) << 16);
      pk.y = (unsigned)f2bf(ov.z) | ((unsigned)f2bf(ov.w) << 16);
      reinterpret_cast<uint2*>(outb + rbase)[c4] = pk;
    }
  }
}

}  // namespace

extern "C" void kernel_launch(void* const* d_in, const int* in_sizes, int n_in,
                              void* d_out, int out_size, void* d_ws, size_t ws_size,
                              hipStream_t stream)
{
  (void)in_sizes; (void)n_in; (void)out_size; (void)ws_size;
  const float* x      = (const float*)d_in[0];
  const float* wqkv_c = (const float*)d_in[2];
  const float* wqkv_p = (const float*)d_in[3];
  const float* wo_c   = (const float*)d_in[4];
  const float* wo_p   = (const float*)d_in[5];
  const float* w1_c   = (const float*)d_in[6];
  const float* b1_c   = (const float*)d_in[7];
  const float* w1_p   = (const float*)d_in[8];
  const float* b1_p   = (const float*)d_in[9];
  const float* w2_c   = (const float*)d_in[10];
  const float* b2_c   = (const float*)d_in[11];
  const float* w2_p   = (const float*)d_in[12];
  const float* b2_p   = (const float*)d_in[13];
  const float* ln1_g  = (const float*)d_in[14];
  const float* ln1_b  = (const float*)d_in[15];
  const float* ln2_g  = (const float*)d_in[16];
  const float* ln2_b  = (const float*)d_in[17];

  // workspace layout (bytes), 116MB
  char* W = (char*)d_ws;
  u16*   xb  = (u16*)(W);                      // 8MB; Ob aliases after QKV
  u16*   Ob  = xb;
  u16*   Qb  = (u16*)(W + (8u  << 20));        // 8MB [b,h,tok,128]
  u16*   Kb  = (u16*)(W + (16u << 20));        // 8MB
  u16*   Vtb = (u16*)(W + (24u << 20));        // 8MB [b,h,d,tok]
  u16*   Bqt = (u16*)(W + (32u << 20));        // 3MB [2][1536][512]
  u16*   wot = (u16*)(W + (35u << 20));        // 1MB [2][512][512]
  u16*   w1b = (u16*)(W + (36u << 20));        // 4MB [2][2048][512]
  u16*   w2b = (u16*)(W + (40u << 20));        // 4MB [2][512][2048]
  float* spA = (float*)(W + (44u << 20));      // 16MB fp32 K-partial 0
  float* spB = (float*)(W + (60u << 20));      // 16MB fp32 K-partial 1
  u16*   x1b = (u16*)(W + (76u << 20));        // 8MB bf16 LN1 output
  u16*   hb  = (u16*)(W + (84u << 20));        // 32MB [4096][4096] (half-interleaved)
  float* out = (float*)d_out;

  k_prep <<<10240, 256, 0, stream>>>(x, w1_c, w1_p, w2_c, w2_p,
                                     wo_c, wo_p, wqkv_c, wqkv_p,
                                     xb, w1b, w2b, wot, Bqt);
  k_qkv_g<<<dim3(32, 12, 2), 256, 0, stream>>>(xb, Bqt, Qb, Kb, Vtb);
  k_attn <<<dim3(16, 32),    256, 0, stream>>>(Qb, Kb, Vtb, Ob);
  k_oproj<<<dim3(32, 4, 4),  256, 0, stream>>>(Ob, wot, spA, spB);
  k_lnsum<<<1024, 256, 0, stream>>>(spA, spB, x, nullptr, nullptr, nullptr,
                                    ln1_g, ln1_b, nullptr, x1b);
  k_ffn1 <<<dim3(32, 16, 2), 256, 0, stream>>>(x1b, w1b, b1_c, b1_p, hb);
  k_ffn2 <<<dim3(32, 4, 4),  256, 0, stream>>>(hb, w2b, spA, spB);
  k_lnsum<<<1024, 256, 0, stream>>>(spA, spB, nullptr, x1b, b2_c, b2_p,
                                    ln2_g, ln2_b, out, nullptr);
}

// Round 12
// 264.316 us; speedup vs baseline: 1.1544x; 1.0033x over previous
//
#include <hip/hip_runtime.h>
#include <math.h>

// PartitionedTransformerEncoderLayer on MI355X — round 12.
// vs round 11: k_attn reverts to SINGLE-buffered K/V + __syncthreads (round-6's
// dbuf halved blocks/CU 4->2 and was itself a regression 58->62us; the swapped
// softmax masked it). LDS 73728 -> 40960 = exactly 4 blocks/CU = 4 waves/SIMD,
// doubling TLP to hide softmax's serial shuffle/exp chains (m114 mechanism).
// Swapped QK^T softmax / P-swizzle / setprio kept. All other kernels untouched.

namespace {

typedef unsigned short u16;
typedef __attribute__((ext_vector_type(8))) short s16x8;
typedef __attribute__((ext_vector_type(4))) float f32x4;

__device__ inline u16 f2bf(float f) {
  union { float f; unsigned u; } c; c.f = f;
  unsigned u = c.u;
  return (u16)((u + 0x7fffu + ((u >> 16) & 1u)) >> 16);
}

__device__ inline float bf2f(u16 v) {
  union { unsigned u; float f; } c; c.u = ((unsigned)v) << 16; return c.f;
}

__device__ inline void gl16(const void* g, void* l) {
  __builtin_amdgcn_global_load_lds(
      (const __attribute__((address_space(1))) unsigned int*)g,
      (__attribute__((address_space(3))) unsigned int*)l, 16, 0, 0);
}

__device__ inline s16x8 ldf(const void* p) { return *(const s16x8*)p; }

__device__ inline f32x4 mfma16(s16x8 a, s16x8 b, f32x4 c) {
  return __builtin_amdgcn_mfma_f32_16x16x32_bf16(a, b, c, 0, 0, 0);
}

#define WAITVM8() asm volatile("s_waitcnt vmcnt(8)" ::: "memory")
#define WAITVM0() asm volatile("s_waitcnt vmcnt(0)" ::: "memory")

// ---------------- GEMM core 1: 128x128, 4 waves, wave-tile 64x64 ----------------
__device__ inline void gemm_core(const char* gA, long stepA, long rs32A,
                                 const char* gB, long stepB, long rs32B,
                                 int ksteps, char* AsB, char* BsB, int t,
                                 f32x4 acc[4][4])
{
  const int l = t & 63;
  const int w = t >> 6;
  const int wr = w >> 1, wc = w & 1;
  const int lswz = (l & 7) << 4;
  const int wofs = w * 1024;
  int aoff[4][2], boff[4][2];
#pragma unroll
  for (int mi = 0; mi < 4; ++mi)
#pragma unroll
    for (int c = 0; c < 2; ++c) {
      aoff[mi][c] = (wr*64 + mi*16 + (l & 15))*128 + ((c*64 + ((l >> 4)*16)) ^ lswz);
      boff[mi][c] = (wc*64 + mi*16 + (l & 15))*128 + ((c*64 + ((l >> 4)*16)) ^ lswz);
    }
  for (int ks = 0; ks < ksteps; ++ks) {
#pragma unroll
    for (int is = 0; is < 4; ++is) {
      gl16(gA + is*rs32A, AsB + is*4096 + wofs);
      gl16(gB + is*rs32B, BsB + is*4096 + wofs);
    }
    gA += stepA; gB += stepB;
    __syncthreads();
    s16x8 af[4][2], bf[4][2];
#pragma unroll
    for (int mi = 0; mi < 4; ++mi)
#pragma unroll
      for (int c = 0; c < 2; ++c) {
        af[mi][c] = ldf(AsB + aoff[mi][c]);
        bf[mi][c] = ldf(BsB + boff[mi][c]);
      }
#pragma unroll
    for (int mi = 0; mi < 4; ++mi)
#pragma unroll
      for (int nj = 0; nj < 4; ++nj)
#pragma unroll
        for (int c = 0; c < 2; ++c)
          acc[mi][nj] = mfma16(af[mi][c], bf[nj][c], acc[mi][nj]);
    __syncthreads();
  }
}

// ---------------- GEMM core DB: 128x128, double-buffered, stage-ahead ----------------
__device__ inline void gemm_core_db(const char* gA, long stepA, long rs32A,
                                    const char* gB, long stepB, long rs32B,
                                    int ksteps, char* AsB, char* BsB, int t,
                                    f32x4 acc[4][4])
{
  const int l = t & 63;
  const int w = t >> 6;
  const int wr = w >> 1, wc = w & 1;
  const int lswz = (l & 7) << 4;
  const int wofs = w * 1024;
  int aoff[4][2], boff[4][2];
#pragma unroll
  for (int mi = 0; mi < 4; ++mi)
#pragma unroll
    for (int c = 0; c < 2; ++c) {
      aoff[mi][c] = (wr*64 + mi*16 + (l & 15))*128 + ((c*64 + ((l >> 4)*16)) ^ lswz);
      boff[mi][c] = (wc*64 + mi*16 + (l & 15))*128 + ((c*64 + ((l >> 4)*16)) ^ lswz);
    }
  auto stage = [&](int ks, int buf) {
    const char* A = gA + (long)ks*stepA;
    const char* B = gB + (long)ks*stepB;
    char* ad = AsB + buf*16384 + wofs;
    char* bd = BsB + buf*16384 + wofs;
#pragma unroll
    for (int is = 0; is < 4; ++is) {
      gl16(A + is*rs32A, ad + is*4096);
      gl16(B + is*rs32B, bd + is*4096);
    }
  };
  stage(0, 0);
  for (int ks = 0; ks < ksteps; ++ks) {
    const int cur = ks & 1;
    if (ks + 1 < ksteps) { stage(ks + 1, cur ^ 1); WAITVM8(); }
    else                 { WAITVM0(); }
    __builtin_amdgcn_sched_barrier(0);
    __builtin_amdgcn_s_barrier();
    const char* Ac = AsB + cur*16384;
    const char* Bc = BsB + cur*16384;
    s16x8 af[4][2], bf[4][2];
#pragma unroll
    for (int mi = 0; mi < 4; ++mi)
#pragma unroll
      for (int c = 0; c < 2; ++c) {
        af[mi][c] = ldf(Ac + aoff[mi][c]);
        bf[mi][c] = ldf(Bc + boff[mi][c]);
      }
    __builtin_amdgcn_s_setprio(1);
#pragma unroll
    for (int mi = 0; mi < 4; ++mi)
#pragma unroll
      for (int nj = 0; nj < 4; ++nj)
#pragma unroll
        for (int c = 0; c < 2; ++c)
          acc[mi][nj] = mfma16(af[mi][c], bf[nj][c], acc[mi][nj]);
    __builtin_amdgcn_s_setprio(0);
    __builtin_amdgcn_s_barrier();
  }
}

// ---------------- merged prep: cast x, cast FFN weights, transpose wo, wqkv ---------
__global__ __launch_bounds__(256) void k_prep(
    const float* __restrict__ x,
    const float* __restrict__ w1c, const float* __restrict__ w1p,
    const float* __restrict__ w2c, const float* __restrict__ w2p,
    const float* __restrict__ woc, const float* __restrict__ wop,
    const float* __restrict__ wqc, const float* __restrict__ wqp,
    u16* __restrict__ xb, u16* __restrict__ w1b, u16* __restrict__ w2b,
    u16* __restrict__ wot, u16* __restrict__ Bqt)
{
  __shared__ float tile[32][33];
  const int bid = blockIdx.x;
  const int t = threadIdx.x;
  if (bid < 4096) {
    const int i = bid*256 + t;
    float4 v = reinterpret_cast<const float4*>(x)[i];
    uint2 pk;
    pk.x = (unsigned)f2bf(v.x) | ((unsigned)f2bf(v.y) << 16);
    pk.y = (unsigned)f2bf(v.z) | ((unsigned)f2bf(v.w) << 16);
    reinterpret_cast<uint2*>(xb)[i] = pk;
  } else if (bid < 8192) {
    const int j = bid - 4096;
    const float* src; u16* dst;
    switch (j >> 10) {
      case 0:  src = w1c; dst = w1b;            break;
      case 1:  src = w1p; dst = w1b + 1048576;  break;
      case 2:  src = w2c; dst = w2b;            break;
      default: src = w2p; dst = w2b + 1048576;  break;
    }
    const int i = (j & 1023)*256 + t;
    float4 v = reinterpret_cast<const float4*>(src)[i];
    uint2 pk;
    pk.x = (unsigned)f2bf(v.x) | ((unsigned)f2bf(v.y) << 16);
    pk.y = (unsigned)f2bf(v.z) | ((unsigned)f2bf(v.w) << 16);
    reinterpret_cast<uint2*>(dst)[i] = pk;
  } else if (bid < 8704) {
    const int j = bid - 8192;
    const int half = j >> 8, rem = j & 255;
    const int r0 = (rem >> 4) * 32, c0 = (rem & 15) * 32;
    const float* in = half ? wop : woc;
    u16* o = wot + (size_t)half * 512 * 512;
    const int tx = t & 31, ty = t >> 5;
#pragma unroll
    for (int jj = 0; jj < 4; ++jj)
      tile[ty + 8*jj][tx] = in[(size_t)(r0 + ty + 8*jj)*512 + c0 + tx];
    __syncthreads();
#pragma unroll
    for (int jj = 0; jj < 4; ++jj)
      o[(size_t)(c0 + ty + 8*jj)*512 + r0 + tx] = f2bf(tile[tx][ty + 8*jj]);
  } else {
    const int j = bid - 8704;
    const int z = j / 96, rem = j - z*96;
    const int by = rem / 6, bx = rem - by*6;
    const int half = z >> 3, h = z & 7;
    const float* in = (half ? wqp : wqc) + (size_t)h * 98304;   // [f=512][ca=192]
    u16* o = Bqt + (size_t)half * 786432 + (size_t)h * 98304;   // [ca=192][f=512]
    const int r0 = by * 32, c0 = bx * 32;
    const int tx = t & 31, ty = t >> 5;
#pragma unroll
    for (int jj = 0; jj < 4; ++jj)
      tile[ty + 8*jj][tx] = in[(size_t)(r0 + ty + 8*jj)*192 + c0 + tx];
    __syncthreads();
#pragma unroll
    for (int jj = 0; jj < 4; ++jj)
      o[(size_t)(c0 + ty + 8*jj)*512 + r0 + tx] = f2bf(tile[tx][ty + 8*jj]);
  }
}

// ---------------- QKV projection GEMM (core1) ----------------
__global__ __launch_bounds__(256) void k_qkv_g(
    const u16* __restrict__ xb, const u16* __restrict__ Bqt,
    u16* __restrict__ Qb, u16* __restrict__ Kb, u16* __restrict__ Vtb)
{
  __shared__ char As[16384], Bs[16384];
  const int t = threadIdx.x;
  const int mt = blockIdx.x, nt = blockIdx.y, half = blockIdx.z;
  const int rowA = t >> 3;
  const int insw = (((t & 7) ^ (rowA & 7)) << 4);
  const char* gA = (const char*)xb + half*1024 + (size_t)(mt*128 + rowA)*2048 + insw;
  const char* gB = (const char*)(Bqt + (size_t)half*786432) + (size_t)(nt*128 + rowA)*1024 + insw;
  f32x4 acc[4][4] = {};
  gemm_core(gA, 128, 32L*2048, gB, 128, 32L*1024, 8, As, Bs, t, acc);
  const int l = t & 63, w = t >> 6, wr = w >> 1, wc = w & 1;
#pragma unroll
  for (int nj = 0; nj < 4; ++nj) {
    const int gc = nt*128 + wc*64 + nj*16 + (l & 15);
    const int h = gc / 192, rem = gc - h*192;
    const int cc = rem >> 6, a = rem & 63;
#pragma unroll
    for (int mi = 0; mi < 4; ++mi) {
#pragma unroll
      for (int r = 0; r < 4; ++r) {
        const int gr = mt*128 + wr*64 + mi*16 + ((l >> 4) << 2) + r;
        const int b = gr >> 10, tok = gr & 1023;
        const float v = acc[mi][nj][r];
        if (cc == 0)
          Qb[((size_t)((b*8 + h)*1024 + tok))*128 + half*64 + a] =
              f2bf(v * 0.08838834764831843f);
        else if (cc == 1)
          Kb[((size_t)((b*8 + h)*1024 + tok))*128 + half*64 + a] = f2bf(v);
        else
          Vtb[((size_t)((b*8 + h)*128 + half*64 + a))*1024 + tok] = f2bf(v);
      }
    }
  }
}

// ------ MFMA flash attention: single-buffer K/V (4 blocks/CU), swapped QK^T ------
__global__ __launch_bounds__(256) void k_attn(
    const u16* __restrict__ Qb, const u16* __restrict__ Kb,
    const u16* __restrict__ Vtb, u16* __restrict__ Ob)
{
  __shared__ char Ks[16384];       // K tile [64 tok][128B d] swizzled
  __shared__ char Vs[16384];       // Vt tile [128 d][128B tok] swizzled
  __shared__ u16 Pl[4 * 16 * 64];  // per-wave P [16 q][64 k] u16, XOR-swizzled (8KB)
  const int t = threadIdx.x;
  const int l = t & 63, w = t >> 6;
  const int g = l >> 4;
  const int qt = blockIdx.x, bh = blockIdx.y;
  const size_t cb = (size_t)bh * 1024 * 128;
  const int q0 = qt*64 + w*16;
  const int lswz = (l & 7) << 4;

  s16x8 qf[4];   // B-frag of Q^T: col q = l&15
#pragma unroll
  for (int dc = 0; dc < 4; ++dc)
    qf[dc] = ldf((const char*)(Qb + cb) + (size_t)(q0 + (l & 15))*256 + dc*64 + (g*16));

  f32x4 o[8];
#pragma unroll
  for (int dc = 0; dc < 8; ++dc) o[dc] = (f32x4){0.f, 0.f, 0.f, 0.f};
  float mrun = -INFINITY, lrun = 0.f;   // per-lane: q = l&15

  const int krow = t >> 4;
  const int kins = (((t & 15) ^ (krow & 7)) << 4);
  const char* gK0 = (const char*)(Kb + cb) + (size_t)krow*256 + kins;
  const int vrow = t >> 3;
  const int vins = (((t & 7) ^ (vrow & 7)) << 4);
  const char* gV0 = (const char*)(Vtb + cb) + (size_t)vrow*2048 + vins;

  char* pwB = (char*)(Pl + w*1024);
  const int prow = (l & 15);
  const int pkey = (prow & 7) << 4;
  const int pread0 = prow*128 + ((0*64 + g*16) ^ pkey);
  const int pread1 = prow*128 + ((1*64 + g*16) ^ pkey);
  const int srcbase = l & 48;

  for (int kt = 0; kt < 16; ++kt) {
    __syncthreads();   // all waves done reading previous tile
#pragma unroll
    for (int is = 0; is < 4; ++is) {
      gl16(gK0 + (size_t)kt*16384 + (size_t)is*16*256, Ks + w*1024 + is*4096);
      gl16(gV0 + (size_t)kt*128 + (size_t)is*32*2048, Vs + w*1024 + is*4096);
    }
    __syncthreads();   // compiler drains vmcnt(0) before barrier -> tile landed

    // QK^T swapped: s[kf] = K_frag * Q^T_frag -> C[k][q], q = l&15 lane-local
    f32x4 s[4];
#pragma unroll
    for (int kf = 0; kf < 4; ++kf) s[kf] = (f32x4){0.f, 0.f, 0.f, 0.f};
    __builtin_amdgcn_s_setprio(1);
#pragma unroll
    for (int dc = 0; dc < 4; ++dc) {
#pragma unroll
      for (int kf = 0; kf < 4; ++kf) {
        s16x8 kfr = ldf(Ks + (kf*16 + (l & 15))*256 + ((dc*64 + g*16) ^ lswz));
        s[kf] = mfma16(kfr, qf[dc], s[kf]);
      }
    }
    __builtin_amdgcn_s_setprio(0);
    // in-lane softmax over 16 regs, then 2 shuffles
    float m01, m23, pmax;
    m01 = fmaxf(fmaxf(s[0][0], s[0][1]), fmaxf(s[0][2], s[0][3]));
    m23 = fmaxf(fmaxf(s[1][0], s[1][1]), fmaxf(s[1][2], s[1][3]));
    pmax = fmaxf(m01, m23);
    m01 = fmaxf(fmaxf(s[2][0], s[2][1]), fmaxf(s[2][2], s[2][3]));
    m23 = fmaxf(fmaxf(s[3][0], s[3][1]), fmaxf(s[3][2], s[3][3]));
    pmax = fmaxf(pmax, fmaxf(m01, m23));
    pmax = fmaxf(pmax, __shfl_xor(pmax, 16));
    pmax = fmaxf(pmax, __shfl_xor(pmax, 32));
    const bool skip = __all(pmax <= mrun + 8.0f);   // defer-max THR=8
    float mnew, alpha;
    if (skip) { mnew = mrun; alpha = 1.0f; }
    else      { mnew = fmaxf(mrun, pmax); alpha = __expf(mrun - mnew); }
    float psum = 0.f;
#pragma unroll
    for (int kf = 0; kf < 4; ++kf) {
#pragma unroll
      for (int r = 0; r < 4; ++r) {
        const float p = __expf(s[kf][r] - mnew);
        s[kf][r] = p;
        psum += p;
      }
    }
    psum += __shfl_xor(psum, 16);
    psum += __shfl_xor(psum, 32);
    lrun = lrun * alpha + psum;
    mrun = mnew;
    if (!skip) {
      float a4[4];
#pragma unroll
      for (int r = 0; r < 4; ++r) a4[r] = __shfl(alpha, srcbase | (g*4 + r));
#pragma unroll
      for (int dc = 0; dc < 8; ++dc)
#pragma unroll
        for (int r = 0; r < 4; ++r) o[dc][r] *= a4[r];
    }
    // P -> per-wave LDS: row q = l&15, 4 x 8B packed
#pragma unroll
    for (int kf = 0; kf < 4; ++kf) {
      uint2 pk;
      pk.x = (unsigned)f2bf(s[kf][0]) | ((unsigned)f2bf(s[kf][1]) << 16);
      pk.y = (unsigned)f2bf(s[kf][2]) | ((unsigned)f2bf(s[kf][3]) << 16);
      *(uint2*)(pwB + prow*128 + ((kf*32 + g*8) ^ pkey)) = pk;
    }
    s16x8 pa[2];
    pa[0] = ldf(pwB + pread0);
    pa[1] = ldf(pwB + pread1);
    // PV
    __builtin_amdgcn_s_setprio(1);
#pragma unroll
    for (int dc = 0; dc < 8; ++dc) {
#pragma unroll
      for (int c = 0; c < 2; ++c) {
        s16x8 vf = ldf(Vs + (dc*16 + (l & 15))*128 + ((c*64 + g*16) ^ lswz));
        o[dc] = mfma16(pa[c], vf, o[dc]);
      }
    }
    __builtin_amdgcn_s_setprio(0);
  }

  float linv[4];
#pragma unroll
  for (int r = 0; r < 4; ++r)
    linv[r] = 1.0f / __shfl(lrun, srcbase | (g*4 + r));
#pragma unroll
  for (int r = 0; r < 4; ++r) {
    const int q = q0 + g*4 + r;
#pragma unroll
    for (int dc = 0; dc < 8; ++dc)
      Ob[cb + (size_t)q*128 + dc*16 + (l & 15)] = f2bf(o[dc][r] * linv[r]);
  }
}

// ------- output projection, K-split x2: grid (32,4,4), z = half*2+kk -------
__global__ __launch_bounds__(256) void k_oproj(
    const u16* __restrict__ Ob, const u16* __restrict__ wot,
    float* __restrict__ spA, float* __restrict__ spB)
{
  __shared__ char As[2*16384], Bs[2*16384];
  const int t = threadIdx.x;
  const int mt = blockIdx.x, nt = blockIdx.y;
  const int half = blockIdx.z >> 1, kk = blockIdx.z & 1;
  const int rowA = t >> 3;
  const int insw = (((t & 7) ^ (rowA & 7)) << 4);
  const int b = mt >> 3;
  const char* gA = (const char*)Ob + ((size_t)(b*8 + kk*4)*1024 + (mt & 7)*128 + rowA)*256
                   + half*128 + insw;
  const char* gB = (const char*)(wot + (size_t)half*262144)
                   + (size_t)(nt*128 + rowA)*1024 + kk*512 + insw;
  f32x4 acc[4][4] = {};
  gemm_core_db(gA, 262144, 32L*256, gB, 128, 32L*1024, 4, As, Bs, t, acc);
  float* sp = kk ? spB : spA;
  const int l = t & 63, w = t >> 6, wr = w >> 1, wc = w & 1;
#pragma unroll
  for (int mi = 0; mi < 4; ++mi)
#pragma unroll
    for (int r = 0; r < 4; ++r) {
      const int gr = mt*128 + wr*64 + mi*16 + ((l >> 4) << 2) + r;
#pragma unroll
      for (int nj = 0; nj < 4; ++nj) {
        const int col = half*512 + nt*128 + wc*64 + nj*16 + (l & 15);
        sp[(size_t)gr*1024 + col] = acc[mi][nj][r];
      }
    }
}

// ---------------- FFN1 (bias+ReLU), core1: grid (32,16,2) ----------------
__global__ __launch_bounds__(256) void k_ffn1(
    const u16* __restrict__ x1b, const u16* __restrict__ w1b,
    const float* __restrict__ b1c, const float* __restrict__ b1p,
    u16* __restrict__ hb)
{
  __shared__ char As[16384], Bs[16384];
  const int t = threadIdx.x;
  const int mt = blockIdx.x, nt = blockIdx.y, half = blockIdx.z;
  const int rowA = t >> 3;
  const int insw = (((t & 7) ^ (rowA & 7)) << 4);
  const char* gA = (const char*)x1b + half*1024 + (size_t)(mt*128 + rowA)*2048 + insw;
  const char* gB = (const char*)w1b + (size_t)half*2097152 + (size_t)(nt*128 + rowA)*1024 + insw;
  const float* bb = half ? b1p : b1c;
  f32x4 acc[4][4] = {};
  gemm_core(gA, 128, 32L*2048, gB, 128, 32L*1024, 8, As, Bs, t, acc);
  const int l = t & 63, w = t >> 6, wr = w >> 1, wc = w & 1;
#pragma unroll
  for (int mi = 0; mi < 4; ++mi)
#pragma unroll
    for (int r = 0; r < 4; ++r) {
      const int gr = mt*128 + wr*64 + mi*16 + ((l >> 4) << 2) + r;
#pragma unroll
      for (int nj = 0; nj < 4; ++nj) {
        const int n = nt*128 + wc*64 + nj*16 + (l & 15);
        hb[(size_t)gr*4096 + half*2048 + n] = f2bf(fmaxf(acc[mi][nj][r] + bb[n], 0.f));
      }
    }
}

// ------- FFN2, K-split x2: grid (32,4,4), z = half*2+kk. Partial -> sp -------
__global__ __launch_bounds__(256) void k_ffn2(
    const u16* __restrict__ hb, const u16* __restrict__ w2b,
    float* __restrict__ spA, float* __restrict__ spB)
{
  __shared__ char As[2*16384], Bs[2*16384];
  const int t = threadIdx.x;
  const int mt = blockIdx.x, nt = blockIdx.y;
  const int half = blockIdx.z >> 1, kk = blockIdx.z & 1;
  const int rowA = t >> 3;
  const int insw = (((t & 7) ^ (rowA & 7)) << 4);
  const char* gA = (const char*)hb + (size_t)(mt*128 + rowA)*8192 + half*4096
                   + kk*2048 + insw;
  const char* gB = (const char*)w2b + (size_t)half*2097152
                   + (size_t)(nt*128 + rowA)*4096 + kk*2048 + insw;
  f32x4 acc[4][4] = {};
  gemm_core_db(gA, 128, 32L*8192, gB, 128, 32L*4096, 16, As, Bs, t, acc);
  float* sp = kk ? spB : spA;
  const int l = t & 63, w = t >> 6, wr = w >> 1, wc = w & 1;
#pragma unroll
  for (int mi = 0; mi < 4; ++mi)
#pragma unroll
    for (int r = 0; r < 4; ++r) {
      const int gr = mt*128 + wr*64 + mi*16 + ((l >> 4) << 2) + r;
#pragma unroll
      for (int nj = 0; nj < 4; ++nj) {
        const int col = half*512 + nt*128 + wc*64 + nj*16 + (l & 15);
        sp[(size_t)gr*1024 + col] = acc[mi][nj][r];
      }
    }
}

// -------- LayerNorm over (a + b [+ xf] [+ bf16 xr] [+ bias]) — wave/row --------
__global__ __launch_bounds__(256) void k_lnsum(
    const float* __restrict__ a, const float* __restrict__ b,
    const float* __restrict__ xf, const u16* __restrict__ xr,
    const float* __restrict__ bc, const float* __restrict__ bp,
    const float* __restrict__ g, const float* __restrict__ be,
    float* __restrict__ outf, u16* __restrict__ outb)
{
  const int t = threadIdx.x;
  const int l = t & 63;
  const int row = blockIdx.x*4 + (t >> 6);
  const size_t rbase = (size_t)row*1024;
  float4 v[4];
  float s = 0.f, ss = 0.f;
#pragma unroll
  for (int j = 0; j < 4; ++j) {
    const int c4 = l + 64*j;
    float4 av = reinterpret_cast<const float4*>(a + rbase)[c4];
    float4 bv = reinterpret_cast<const float4*>(b + rbase)[c4];
    av.x += bv.x; av.y += bv.y; av.z += bv.z; av.w += bv.w;
    if (xf) {
      float4 xv = reinterpret_cast<const float4*>(xf + rbase)[c4];
      av.x += xv.x; av.y += xv.y; av.z += xv.z; av.w += xv.w;
    }
    if (xr) {
      uint2 pk = reinterpret_cast<const uint2*>(xr + rbase)[c4];
      av.x += bf2f((u16)(pk.x & 0xffff));
      av.y += bf2f((u16)(pk.x >> 16));
      av.z += bf2f((u16)(pk.y & 0xffff));
      av.w += bf2f((u16)(pk.y >> 16));
    }
    if (bc) {
      const float4 bbv = (j < 2) ? reinterpret_cast<const float4*>(bc)[c4]
                                 : reinterpret_cast<const float4*>(bp)[c4 - 128];
      av.x += bbv.x; av.y += bbv.y; av.z += bbv.z; av.w += bbv.w;
    }
    v[j] = av;
    s  += av.x + av.y + av.z + av.w;
    ss += av.x*av.x + av.y*av.y + av.z*av.z + av.w*av.w;
  }
#pragma unroll
  for (int off = 1; off < 64; off <<= 1) {
    s  += __shfl_xor(s, off);
    ss += __shfl_xor(ss, off);
  }
  const float mu = s * (1.f/1024.f);
  const float var = ss * (1.f/1024.f) - mu*mu;
  const float rs = rsqrtf(var + 1e-5f);
#pragma unroll
  for (int j = 0; j < 4; ++j) {
    const int c4 = l + 64*j;
    float4 gv = reinterpret_cast<const float4*>(g)[c4];
    float4 bv = reinterpret_cast<const float4*>(be)[c4];
    float4 ov;
    ov.x = (v[j].x - mu)*rs*gv.x + bv.x;
    ov.y = (v[j].y - mu)*rs*gv.y + bv.y;
    ov.z = (v[j].z - mu)*rs*gv.z + bv.z;
    ov.w = (v[j].w - mu)*rs*gv.w + bv.w;
    if (outf)
      reinterpret_cast<float4*>(outf + rbase)[c4] = ov;
    if (outb) {
      uint2 pk;
      pk.x = (unsigned)f2bf(ov.x) | ((unsigned)f2bf(ov.y) << 16);
      pk.y = (unsigned)f2bf(ov.z) | ((unsigned)f2bf(ov.w) << 16);
      reinterpret_cast<uint2*>(outb + rbase)[c4] = pk;
    }
  }
}

}  // namespace

extern "C" void kernel_launch(void* const* d_in, const int* in_sizes, int n_in,
                              void* d_out, int out_size, void* d_ws, size_t ws_size,
                              hipStream_t stream)
{
  (void)in_sizes; (void)n_in; (void)out_size; (void)ws_size;
  const float* x      = (const float*)d_in[0];
  const float* wqkv_c = (const float*)d_in[2];
  const float* wqkv_p = (const float*)d_in[3];
  const float* wo_c   = (const float*)d_in[4];
  const float* wo_p   = (const float*)d_in[5];
  const float* w1_c   = (const float*)d_in[6];
  const float* b1_c   = (const float*)d_in[7];
  const float* w1_p   = (const float*)d_in[8];
  const float* b1_p   = (const float*)d_in[9];
  const float* w2_c   = (const float*)d_in[10];
  const float* b2_c   = (const float*)d_in[11];
  const float* w2_p   = (const float*)d_in[12];
  const float* b2_p   = (const float*)d_in[13];
  const float* ln1_g  = (const float*)d_in[14];
  const float* ln1_b  = (const float*)d_in[15];
  const float* ln2_g  = (const float*)d_in[16];
  const float* ln2_b  = (const float*)d_in[17];

  // workspace layout (bytes), 116MB
  char* W = (char*)d_ws;
  u16*   xb  = (u16*)(W);                      // 8MB; Ob aliases after QKV
  u16*   Ob  = xb;
  u16*   Qb  = (u16*)(W + (8u  << 20));        // 8MB [b,h,tok,128]
  u16*   Kb  = (u16*)(W + (16u << 20));        // 8MB
  u16*   Vtb = (u16*)(W + (24u << 20));        // 8MB [b,h,d,tok]
  u16*   Bqt = (u16*)(W + (32u << 20));        // 3MB [2][1536][512]
  u16*   wot = (u16*)(W + (35u << 20));        // 1MB [2][512][512]
  u16*   w1b = (u16*)(W + (36u << 20));        // 4MB [2][2048][512]
  u16*   w2b = (u16*)(W + (40u << 20));        // 4MB [2][512][2048]
  float* spA = (float*)(W + (44u << 20));      // 16MB fp32 K-partial 0
  float* spB = (float*)(W + (60u << 20));      // 16MB fp32 K-partial 1
  u16*   x1b = (u16*)(W + (76u << 20));        // 8MB bf16 LN1 output
  u16*   hb  = (u16*)(W + (84u << 20));        // 32MB [4096][4096] (half-interleaved)
  float* out = (float*)d_out;

  k_prep <<<10240, 256, 0, stream>>>(x, w1_c, w1_p, w2_c, w2_p,
                                     wo_c, wo_p, wqkv_c, wqkv_p,
                                     xb, w1b, w2b, wot, Bqt);
  k_qkv_g<<<dim3(32, 12, 2), 256, 0, stream>>>(xb, Bqt, Qb, Kb, Vtb);
  k_attn <<<dim3(16, 32),    256, 0, stream>>>(Qb, Kb, Vtb, Ob);
  k_oproj<<<dim3(32, 4, 4),  256, 0, stream>>>(Ob, wot, spA, spB);
  k_lnsum<<<1024, 256, 0, stream>>>(spA, spB, x, nullptr, nullptr, nullptr,
                                    ln1_g, ln1_b, nullptr, x1b);
  k_ffn1 <<<dim3(32, 16, 2), 256, 0, stream>>>(x1b, w1b, b1_c, b1_p, hb);
  k_ffn2 <<<dim3(32, 4, 4),  256, 0, stream>>>(hb, w2b, spA, spB);
  k_lnsum<<<1024, 256, 0, stream>>>(spA, spB, nullptr, x1b, b2_c, b2_p,
                                    ln2_g, ln2_b, out, nullptr);
}